// Round 2
// baseline (2415.671 us; speedup 1.0000x reference)
//
#include <hip/hip_runtime.h>
#include <hip/hip_bf16.h>
#include <math.h>

// ---------------------------------------------------------------------------
// Mamba2 layer (round 1): correctness-first f32, with ADAPTIVE batch-group
// processing so the workspace arena fits whatever ws_size the harness gives.
// Per-batch arena ~47.6 MB; NB = largest of {8,4,2,1} that fits.
// ---------------------------------------------------------------------------

namespace {
constexpr int BB = 8;
constexpr int S = 2048;
constexpr int DM = 512;
constexpr int DIP = 2320;        // in_proj output dim
constexpr int DI = 1024;         // d_inner
constexpr int CDIM = 1280;       // conv dim
constexpr int NH = 16;
constexpr int HD = 64;
constexpr int DSTATE = 128;
constexpr int CH = 128;          // chunk length
constexpr int NC = S / CH;       // 16 chunks
constexpr int FF = 2048;
constexpr float EPS = 1e-5f;
}

__device__ __forceinline__ float gelu_exact(float x) {
    return 0.5f * x * (1.0f + erff(x * 0.7071067811865476f));
}

__device__ __forceinline__ void block_sum2(float& a, float& b) {
    #pragma unroll
    for (int o = 32; o > 0; o >>= 1) {
        a += __shfl_down(a, o, 64);
        b += __shfl_down(b, o, 64);
    }
    __shared__ float sa[4], sb[4];
    int w = threadIdx.x >> 6;
    if ((threadIdx.x & 63) == 0) { sa[w] = a; sb[w] = b; }
    __syncthreads();
    a = sa[0] + sa[1] + sa[2] + sa[3];
    b = sb[0] + sb[1] + sb[2] + sb[3];
}

// ---------------------------------------------------------------------------
// Generic f32 GEMM: C[m,n] = act(sum_k A[m,k] * W[n,k] + bias[n])
// 64x64 tile, BK=16, 256 threads, 4x4 per thread. M%64==0, K%16==0.
// N may be ragged. Strided-batched via blockIdx.z. ACT: 0=none, 1=exact gelu.
// ---------------------------------------------------------------------------
template <int ACT, bool HASBIAS>
__global__ __launch_bounds__(256)
void gemm_kernel(const float* __restrict__ A, const float* __restrict__ W,
                 const float* __restrict__ bias, float* __restrict__ C,
                 int M, int N, int K, int lda, int ldw, int ldc,
                 long batchA, long batchW, long batchC)
{
    A += (long)blockIdx.z * batchA;
    W += (long)blockIdx.z * batchW;
    C += (long)blockIdx.z * batchC;
    __shared__ __align__(16) float As[16][68];
    __shared__ __align__(16) float Ws[16][68];
    const int tid = threadIdx.x;
    const int bm = blockIdx.y * 64;
    const int bn = blockIdx.x * 64;
    const int tm = (tid & 15) * 4;
    const int tn = (tid >> 4) * 4;
    const int lr = tid >> 2;         // 0..63 row within tile
    const int lk = (tid & 3) * 4;    // 0,4,8,12
    const float* Ap = A + (long)(bm + lr) * lda + lk;
    const float* Wp = W + (long)(bn + lr) * ldw + lk;
    const bool wv_ok = (bn + lr) < N;
    float acc[4][4];
    #pragma unroll
    for (int i = 0; i < 4; i++)
        #pragma unroll
        for (int j = 0; j < 4; j++) acc[i][j] = 0.f;

    for (int k0 = 0; k0 < K; k0 += 16) {
        float4 av = *(const float4*)(Ap + k0);
        float4 wv = wv_ok ? *(const float4*)(Wp + k0) : make_float4(0.f, 0.f, 0.f, 0.f);
        As[lk + 0][lr] = av.x; As[lk + 1][lr] = av.y;
        As[lk + 2][lr] = av.z; As[lk + 3][lr] = av.w;
        Ws[lk + 0][lr] = wv.x; Ws[lk + 1][lr] = wv.y;
        Ws[lk + 2][lr] = wv.z; Ws[lk + 3][lr] = wv.w;
        __syncthreads();
        #pragma unroll
        for (int k = 0; k < 16; k++) {
            float4 a = *(const float4*)&As[k][tm];
            float4 w = *(const float4*)&Ws[k][tn];
            acc[0][0] += a.x * w.x; acc[0][1] += a.x * w.y; acc[0][2] += a.x * w.z; acc[0][3] += a.x * w.w;
            acc[1][0] += a.y * w.x; acc[1][1] += a.y * w.y; acc[1][2] += a.y * w.z; acc[1][3] += a.y * w.w;
            acc[2][0] += a.z * w.x; acc[2][1] += a.z * w.y; acc[2][2] += a.z * w.z; acc[2][3] += a.z * w.w;
            acc[3][0] += a.w * w.x; acc[3][1] += a.w * w.y; acc[3][2] += a.w * w.z; acc[3][3] += a.w * w.w;
        }
        __syncthreads();
    }
    #pragma unroll
    for (int i = 0; i < 4; i++) {
        long row = bm + tm + i;
        #pragma unroll
        for (int j = 0; j < 4; j++) {
            int col = bn + tn + j;
            if (col < N) {
                float v = acc[i][j];
                if (HASBIAS) v += bias[col];
                if (ACT == 1) v = gelu_exact(v);
                C[row * ldc + col] = v;
            }
        }
    }
}

// ---------------------------------------------------------------------------
// Causal depthwise conv (width 4) + SiLU over xBC columns of zxbcdt.
// count = Tg*CDIM elements; sequences are whole, so s = (idx/CDIM) % S.
// ---------------------------------------------------------------------------
__global__ __launch_bounds__(256)
void conv_silu_kernel(const float* __restrict__ zx, const float* __restrict__ cw,
                      const float* __restrict__ cb, float* __restrict__ xBC, long count)
{
    long idx = (long)blockIdx.x * 256 + threadIdx.x;
    if (idx >= count) return;
    int c = (int)(idx % CDIM);
    long t = idx / CDIM;
    int s = (int)(t % S);
    float v = cb[c];
    #pragma unroll
    for (int k = 0; k < 4; k++) {
        int sp = s + k - 3;
        if (sp >= 0) v += zx[(t + k - 3) * DIP + DI + c] * cw[c * 4 + k];
    }
    v = v / (1.f + __expf(-v));
    xBC[idx] = v;
}

__global__ __launch_bounds__(256)
void dt_kernel(const float* __restrict__ zx, const float* __restrict__ dt_bias,
               float* __restrict__ dts, long count)
{
    long idx = (long)blockIdx.x * 256 + threadIdx.x;
    if (idx >= count) return;
    int h = (int)(idx & 15);
    long t = idx >> 4;
    float x = zx[t * DIP + (DI + CDIM) + h] + dt_bias[h];
    dts[idx] = (x > 20.f) ? x : log1pf(__expf(x));
}

// ---------------------------------------------------------------------------
// Intra-chunk SSD: one block per (b_local,c,h). bid = b*256 + c*16 + h.
// ---------------------------------------------------------------------------
__global__ __launch_bounds__(256)
void ssd_intra(const float* __restrict__ xBC, const float* __restrict__ dts,
               const float* __restrict__ G, const float* __restrict__ A_log,
               const float* __restrict__ D_head,
               float* __restrict__ y, float* __restrict__ statesT,
               float* __restrict__ acs_all, float* __restrict__ cdlog)
{
    const int bid = blockIdx.x;
    const int h = bid & 15;
    const int c = (bid >> 4) & 15;
    const int b = bid >> 8;
    const int tid = threadIdx.x;
    __shared__ float dtv[128];
    __shared__ float acs[128];
    __shared__ __align__(16) float Xs[128][64];
    const long t0 = (long)b * S + (long)c * CH;
    const float Ah = -__expf(A_log[h]);

    if (tid < 128) {
        float d = dts[(t0 + tid) * NH + h];
        dtv[tid] = d;
        acs[tid] = d * Ah;
    }
    __syncthreads();
    for (int off = 1; off < 128; off <<= 1) {
        float add = 0.f;
        if (tid < 128 && tid >= off) add = acs[tid - off];
        __syncthreads();
        if (tid < 128 && tid >= off) acs[tid] += add;
        __syncthreads();
    }
    for (int i = tid; i < 128 * 64; i += 256) {
        int r = i >> 6, p = i & 63;
        Xs[r][p] = xBC[(t0 + r) * CDIM + h * HD + p];
    }
    __syncthreads();
    if (tid < 128) acs_all[(long)bid * 128 + tid] = acs[tid];
    if (tid == 0) cdlog[bid] = acs[127];

    const int r = tid >> 1;
    const int p0 = (tid & 1) * 32;
    const float er = acs[r];
    const float el = acs[127];
    const float* Grow = G + ((long)(b * NC + c) * 128 + r) * 128;

    float acc[32];
    #pragma unroll
    for (int q = 0; q < 32; q++) acc[q] = 0.f;
    for (int j = 0; j <= r; j++) {
        float w = Grow[j] * __expf(er - acs[j]) * dtv[j];
        #pragma unroll
        for (int q = 0; q < 32; q++) acc[q] += w * Xs[j][p0 + q];
    }
    {
        const float Dh = D_head[h];
        long base = (t0 + r) * DI + h * HD + p0;
        #pragma unroll
        for (int q = 0; q < 32; q++) y[base + q] = acc[q] + Dh * Xs[r][p0 + q];
    }
    const int n = r;
    #pragma unroll
    for (int q = 0; q < 32; q++) acc[q] = 0.f;
    for (int j = 0; j < 128; j++) {
        float w = xBC[(t0 + j) * CDIM + DI + n] * __expf(el - acs[j]) * dtv[j];
        #pragma unroll
        for (int q = 0; q < 32; q++) acc[q] += w * Xs[j][p0 + q];
    }
    long sbase = (long)bid * 8192 + (long)n * 64 + p0;
    #pragma unroll
    for (int q = 0; q < 32; q++) statesT[sbase + q] = acc[q];
}

// ---------------------------------------------------------------------------
// Inter-chunk sequential scan; in-place. One block per (b_local,h).
// ---------------------------------------------------------------------------
__global__ __launch_bounds__(256)
void ssd_scan(float* __restrict__ statesT, const float* __restrict__ cdlog)
{
    const int h = blockIdx.x & 15;
    const int b = blockIdx.x >> 4;
    const int tid = threadIdx.x;
    float prev[32];
    #pragma unroll
    for (int q = 0; q < 32; q++) prev[q] = 0.f;
    for (int c = 0; c < NC; c++) {
        int bc = (b * NC + c) * NH + h;
        float cd = __expf(cdlog[bc]);
        long base = (long)bc * 8192;
        #pragma unroll
        for (int q = 0; q < 32; q++) {
            long idx = base + (long)q * 256 + tid;
            float st = statesT[idx];
            statesT[idx] = prev[q];
            prev[q] = cd * prev[q] + st;
        }
    }
}

// ---------------------------------------------------------------------------
// Off-chunk contribution: y += exp(acs_i) * sum_n C[i,n] * prev[n][p]
// ---------------------------------------------------------------------------
__global__ __launch_bounds__(256)
void ssd_off(const float* __restrict__ xBC, const float* __restrict__ prevT,
             const float* __restrict__ acs_all, float* __restrict__ y)
{
    const int bid = blockIdx.x;
    const int h = bid & 15;
    const int c = (bid >> 4) & 15;
    const int b = bid >> 8;
    const int tid = threadIdx.x;
    __shared__ __align__(16) float Ps[128][64];
    __shared__ float acs[128];
    const long t0 = (long)b * S + (long)c * CH;
    for (int i = tid; i < 8192; i += 256) Ps[i >> 6][i & 63] = prevT[(long)bid * 8192 + i];
    if (tid < 128) acs[tid] = acs_all[(long)bid * 128 + tid];
    __syncthreads();
    const int r = tid >> 1;
    const int p0 = (tid & 1) * 32;
    const float* Crow = xBC + (t0 + r) * CDIM + DI + DSTATE;
    float acc[32];
    #pragma unroll
    for (int q = 0; q < 32; q++) acc[q] = 0.f;
    for (int n = 0; n < 128; n++) {
        float w = Crow[n];
        #pragma unroll
        for (int q = 0; q < 32; q++) acc[q] += w * Ps[n][p0 + q];
    }
    float e = __expf(acs[r]);
    long base = (t0 + r) * DI + h * HD + p0;
    #pragma unroll
    for (int q = 0; q < 32; q++) y[base + q] += e * acc[q];
}

// ---------------------------------------------------------------------------
__global__ __launch_bounds__(256)
void gated_rms(const float* __restrict__ y, const float* __restrict__ zx,
               const float* __restrict__ norm_w, float* __restrict__ yn)
{
    const long t = blockIdx.x;
    const int tid = threadIdx.x;
    float g[4];
    float ss = 0.f, dummy = 0.f;
    #pragma unroll
    for (int q = 0; q < 4; q++) {
        int d = tid + q * 256;
        float zv = zx[t * DIP + d];
        float yv = y[t * DI + d];
        float gv = yv * (zv / (1.f + __expf(-zv)));
        g[q] = gv;
        ss += gv * gv;
    }
    block_sum2(ss, dummy);
    float scale = rsqrtf(ss * (1.f / DI) + EPS);
    #pragma unroll
    for (int q = 0; q < 4; q++) {
        int d = tid + q * 256;
        yn[t * DI + d] = g[q] * scale * norm_w[d];
    }
}

__global__ __launch_bounds__(256)
void add_ln(const float* __restrict__ x, const float* __restrict__ r,
            const float* __restrict__ w, const float* __restrict__ bpar,
            float* __restrict__ out)
{
    const long t = blockIdx.x;
    const int tid = threadIdx.x;
    float v[2];
    float s = 0.f, s2 = 0.f;
    #pragma unroll
    for (int q = 0; q < 2; q++) {
        int d = tid + q * 256;
        float vv = x[t * DM + d] + r[t * DM + d];
        v[q] = vv;
        s += vv;
        s2 += vv * vv;
    }
    block_sum2(s, s2);
    float mean = s * (1.f / DM);
    float var = s2 * (1.f / DM) - mean * mean;
    float inv = rsqrtf(var + EPS);
    #pragma unroll
    for (int q = 0; q < 2; q++) {
        int d = tid + q * 256;
        out[t * DM + d] = (v[q] - mean) * inv * w[d] + bpar[d];
    }
}

// ---------------------------------------------------------------------------

extern "C" void kernel_launch(void* const* d_in, const int* in_sizes, int n_in,
                              void* d_out, int out_size, void* d_ws, size_t ws_size,
                              hipStream_t stream)
{
    const float* tgt       = (const float*)d_in[0];
    const float* in_proj_w = (const float*)d_in[5];
    const float* conv_w    = (const float*)d_in[6];
    const float* conv_b    = (const float*)d_in[7];
    const float* dt_bias   = (const float*)d_in[8];
    const float* A_log     = (const float*)d_in[9];
    const float* D_head    = (const float*)d_in[10];
    const float* norm_w    = (const float*)d_in[11];
    const float* out_proj_w= (const float*)d_in[12];
    const float* norm1_w   = (const float*)d_in[13];
    const float* norm1_b   = (const float*)d_in[14];
    const float* w1        = (const float*)d_in[15];
    const float* b1        = (const float*)d_in[16];
    const float* w2        = (const float*)d_in[17];
    const float* b2        = (const float*)d_in[18];
    const float* norm3_w   = (const float*)d_in[19];
    const float* norm3_b   = (const float*)d_in[20];
    float* out = (float*)d_out;

    // Per-batch arena (floats):
    //   zx   S*DIP        = 4,751,360
    //   xBC  S*CDIM       = 2,621,440
    //   dts  S*NH         = 32,768
    //   G    NC*128*128   = 262,144
    //   acs  NC*NH*128    = 32,768
    //   cdl  NC*NH        = 256
    //   y    S*DI         = 2,097,152
    //   st   S*DI         = 2,097,152
    const size_t PB = (size_t)S * DIP + (size_t)S * CDIM + (size_t)S * NH
                    + (size_t)NC * 128 * 128 + (size_t)NC * NH * 128 + (size_t)NC * NH
                    + (size_t)S * DI + (size_t)S * DI;   // 11,895,040 floats/batch
    int NB = 0;
    for (int nb = 8; nb >= 1; nb >>= 1) {
        if (ws_size >= (size_t)nb * PB * sizeof(float)) { NB = nb; break; }
    }
    if (NB == 0) return;  // cannot fit even one batch — nothing we can do

    for (int b0 = 0; b0 < BB; b0 += NB) {
        const long Tg = (long)NB * S;
        float* ws = (float*)d_ws;
        size_t o = 0;
        float* zx   = ws + o; o += (size_t)Tg * DIP;
        float* xBC  = ws + o; o += (size_t)Tg * CDIM;
        float* dts  = ws + o; o += (size_t)Tg * NH;
        float* G    = ws + o; o += (size_t)NB * NC * 128 * 128;
        float* acs  = ws + o; o += (size_t)NB * NC * NH * 128;
        float* cdl  = ws + o; o += (size_t)NB * NC * NH;
        float* ybuf = ws + o; o += (size_t)Tg * DI;
        float* st   = ws + o; o += (size_t)Tg * DI;

        // lifetime-disjoint aliases within the group arena
        float* h1 = zx;     // Tg*FF (2048) fits in zx (2320-wide)   [steps 11-12]
        float* tb = xBC;    // Tg*DM                                  [steps 10-13]
        float* t2 = ybuf;   // Tg*DM                                  [steps 9-10]
        float* yn = st;     // Tg*DI                                  [steps 8-9]
        float* fb = ybuf;   // Tg*DM                                  [steps 12-13]

        const float* tgt_g = tgt + (long)b0 * S * DM;
        float* out_g = out + (long)b0 * S * DM;

        // 1. in_proj GEMM: zx[Tg,2320] = tgt_g @ in_proj_w^T
        gemm_kernel<0, false><<<dim3((DIP + 63) / 64, Tg / 64, 1), 256, 0, stream>>>(
            tgt_g, in_proj_w, nullptr, zx, Tg, DIP, DM, DM, DM, DIP, 0, 0, 0);
        // 2. conv + silu
        conv_silu_kernel<<<(Tg * CDIM) / 256, 256, 0, stream>>>(zx, conv_w, conv_b, xBC, Tg * CDIM);
        // 3. dt softplus
        dt_kernel<<<(Tg * NH) / 256, 256, 0, stream>>>(zx, dt_bias, dts, Tg * NH);
        // 4. per-chunk G = C @ B^T (batched over NB*NC chunks)
        gemm_kernel<0, false><<<dim3(2, 2, NB * NC), 256, 0, stream>>>(
            xBC + DI + DSTATE, xBC + DI, nullptr, G,
            128, 128, 128, CDIM, CDIM, 128,
            (long)CH * CDIM, (long)CH * CDIM, (long)128 * 128);
        // 5. intra-chunk SSD
        ssd_intra<<<NB * NC * NH, 256, 0, stream>>>(xBC, dts, G, A_log, D_head, ybuf, st, acs, cdl);
        // 6. inter-chunk scan
        ssd_scan<<<NB * NH, 256, 0, stream>>>(st, cdl);
        // 7. off-chunk contribution
        ssd_off<<<NB * NC * NH, 256, 0, stream>>>(xBC, st, acs, ybuf);
        // 8. gated RMSNorm -> yn (overwrites statesT)
        gated_rms<<<Tg, 256, 0, stream>>>(ybuf, zx, norm_w, yn);
        // 9. out_proj: t2[Tg,512] = yn @ out_proj_w^T
        gemm_kernel<0, false><<<dim3(DM / 64, Tg / 64, 1), 256, 0, stream>>>(
            yn, out_proj_w, nullptr, t2, Tg, DM, DI, DI, DI, DM, 0, 0, 0);
        // 10. t = LN(tgt + t2)
        add_ln<<<Tg, 256, 0, stream>>>(tgt_g, t2, norm1_w, norm1_b, tb);
        // 11. h1 = gelu(t @ w1^T + b1)
        gemm_kernel<1, true><<<dim3(FF / 64, Tg / 64, 1), 256, 0, stream>>>(
            tb, w1, b1, h1, Tg, FF, DM, DM, DM, FF, 0, 0, 0);
        // 12. f = h1 @ w2^T + b2
        gemm_kernel<0, true><<<dim3(DM / 64, Tg / 64, 1), 256, 0, stream>>>(
            h1, w2, b2, fb, Tg, DM, FF, FF, FF, DM, 0, 0, 0);
        // 13. out = LN(t + f)
        add_ln<<<Tg, 256, 0, stream>>>(tb, fb, norm3_w, norm3_b, out_g);
    }
}

// Round 3
// 1146.426 us; speedup vs baseline: 2.1071x; 2.1071x over previous
//
#include <hip/hip_runtime.h>
#include <hip/hip_bf16.h>
#include <math.h>

// ---------------------------------------------------------------------------
// Mamba2 layer (round 2): big GEMMs moved to bf16 MFMA (m97 recipe:
// 128x128 tile, BK=32, global_load_lds width 16, mfma_f32_16x16x32_bf16).
// dt path stays f32 (feeds exp(cumsum) — error-amplifying). SSD/LN f32.
// Adaptive batch-group loop retained (~35 MB/batch + 7.7 MB weights).
// ---------------------------------------------------------------------------

namespace {
constexpr int BB = 8;
constexpr int S = 2048;
constexpr int DM = 512;
constexpr int DIP = 2320;        // in_proj output dim
constexpr int DIPP = 2432;       // padded to 19*128 for MFMA tiles
constexpr int DI = 1024;         // d_inner
constexpr int CDIM = 1280;       // conv dim
constexpr int NH = 16;
constexpr int HD = 64;
constexpr int DSTATE = 128;
constexpr int CH = 128;          // chunk length
constexpr int NC = S / CH;       // 16 chunks
constexpr int FF = 2048;
constexpr float EPS = 1e-5f;
}

using bf16_t = __hip_bfloat16;
typedef __attribute__((ext_vector_type(8))) short short8;   // 8 bf16 = 4 VGPR
typedef __attribute__((ext_vector_type(4))) float f32x4;

__device__ __forceinline__ float gelu_exact(float x) {
    return 0.5f * x * (1.0f + erff(x * 0.7071067811865476f));
}

__device__ __forceinline__ void gl2lds16(const void* g, void* l) {
    typedef const __attribute__((address_space(1))) unsigned int* gp_t;
    typedef __attribute__((address_space(3))) unsigned int* lp_t;
    __builtin_amdgcn_global_load_lds((gp_t)g, (lp_t)l, 16, 0, 0);
}

__device__ __forceinline__ void block_sum2(float& a, float& b) {
    #pragma unroll
    for (int o = 32; o > 0; o >>= 1) {
        a += __shfl_down(a, o, 64);
        b += __shfl_down(b, o, 64);
    }
    __shared__ float sa[4], sb[4];
    int w = threadIdx.x >> 6;
    if ((threadIdx.x & 63) == 0) { sa[w] = a; sb[w] = b; }
    __syncthreads();
    a = sa[0] + sa[1] + sa[2] + sa[3];
    b = sb[0] + sb[1] + sb[2] + sb[3];
}

// ---------------------------------------------------------------------------
// bf16 MFMA GEMM: C[m,n] = act(sum_k A[m,k]*W[n,k] + bias[n])
// A:[M,K] bf16 row-major, W:[N,K] bf16 row-major (B^T form), C f32 or bf16.
// 128x128 tile, BK=32, 256 threads (4 waves, each 64x64 = 4x4 MFMA tiles).
// LDS layout [q][row][8] (q = k/8 subgroup) to satisfy the wave-uniform-base
// lane-ordered global_load_lds constraint. Requires: M%128==0, K%32==0,
// grid.x covers padded N (loads must be in-bounds; pad W), store guarded by N.
// Strided-batched via blockIdx.z.  ACT: 0=none 1=gelu.
// ---------------------------------------------------------------------------
template <int ACT, bool HASBIAS, bool OUTBF>
__global__ __launch_bounds__(256)
void mfma_gemm(const bf16_t* __restrict__ A, const bf16_t* __restrict__ W,
               const float* __restrict__ bias, void* __restrict__ Cout,
               int N, int K, int lda, int ldw, int ldc,
               long batchA, long batchW, long batchC)
{
    A += (long)blockIdx.z * batchA;
    W += (long)blockIdx.z * batchW;
    __shared__ bf16_t As[4096];   // [4][128][8]
    __shared__ bf16_t Ws[4096];
    const int tid = threadIdx.x;
    const int lane = tid & 63;
    const int wave = tid >> 6;
    const long bm = (long)blockIdx.y * 128;
    const int bn = blockIdx.x * 128;

    // staging geometry: chunk = tid + j*256 (j=0,1); row = chunk&127, q = chunk>>7
    const int srow = tid & 127;
    const int q0 = tid >> 7;          // j=0
    const int q1 = q0 + 2;            // j=1
    const bf16_t* Ag0 = A + (bm + srow) * (long)lda + q0 * 8;
    const bf16_t* Ag1 = A + (bm + srow) * (long)lda + q1 * 8;
    const bf16_t* Wg0 = W + ((long)bn + srow) * (long)ldw + q0 * 8;
    const bf16_t* Wg1 = W + ((long)bn + srow) * (long)ldw + q1 * 8;
    bf16_t* lA0 = &As[(wave * 64) * 8];
    bf16_t* lA1 = &As[(wave * 64 + 256) * 8];
    bf16_t* lW0 = &Ws[(wave * 64) * 8];
    bf16_t* lW1 = &Ws[(wave * 64 + 256) * 8];

    const int kq = lane >> 4;         // 0..3 (k subgroup)
    const int lr = lane & 15;
    const int wm = (wave & 1) * 64;
    const int wn = (wave >> 1) * 64;

    f32x4 acc[4][4];
    #pragma unroll
    for (int i = 0; i < 4; i++)
        #pragma unroll
        for (int j = 0; j < 4; j++) acc[i][j] = (f32x4){0.f, 0.f, 0.f, 0.f};

    for (int k0 = 0; k0 < K; k0 += 32) {
        gl2lds16(Ag0 + k0, lA0);
        gl2lds16(Ag1 + k0, lA1);
        gl2lds16(Wg0 + k0, lW0);
        gl2lds16(Wg1 + k0, lW1);
        __syncthreads();
        short8 af[4], bfr[4];
        #pragma unroll
        for (int i = 0; i < 4; i++)
            af[i] = *(const short8*)&As[(kq * 128 + wm + i * 16 + lr) * 8];
        #pragma unroll
        for (int j = 0; j < 4; j++)
            bfr[j] = *(const short8*)&Ws[(kq * 128 + wn + j * 16 + lr) * 8];
        #pragma unroll
        for (int i = 0; i < 4; i++)
            #pragma unroll
            for (int j = 0; j < 4; j++)
                acc[i][j] = __builtin_amdgcn_mfma_f32_16x16x32_bf16(af[i], bfr[j], acc[i][j], 0, 0, 0);
        __syncthreads();
    }

    // epilogue: C/D layout col=lane&15, row=(lane>>4)*4+reg (m89-verified)
    #pragma unroll
    for (int i = 0; i < 4; i++) {
        #pragma unroll
        for (int j = 0; j < 4; j++) {
            int col = bn + wn + j * 16 + lr;
            if (col < N) {
                float bv = HASBIAS ? bias[col] : 0.f;
                #pragma unroll
                for (int r = 0; r < 4; r++) {
                    long row = bm + wm + i * 16 + kq * 4 + r;
                    float v = acc[i][j][r] + bv;
                    if (ACT == 1) v = gelu_exact(v);
                    if (OUTBF) ((bf16_t*)Cout)[row * (long)ldc + col + blockIdx.z * batchC] = __float2bfloat16(v);
                    else       ((float*)Cout)[row * (long)ldc + col + blockIdx.z * batchC] = v;
                }
            }
        }
    }
}

// ---------------------------------------------------------------------------
// f32 GEMM (kept for the tiny dt projection, N=16): 64x64 tile, BK=16.
// ---------------------------------------------------------------------------
template <int ACT, bool HASBIAS>
__global__ __launch_bounds__(256)
void gemm_kernel(const float* __restrict__ A, const float* __restrict__ W,
                 const float* __restrict__ bias, float* __restrict__ C,
                 int M, int N, int K, int lda, int ldw, int ldc,
                 long batchA, long batchW, long batchC)
{
    A += (long)blockIdx.z * batchA;
    W += (long)blockIdx.z * batchW;
    C += (long)blockIdx.z * batchC;
    __shared__ __align__(16) float Asm[16][68];
    __shared__ __align__(16) float Wsm[16][68];
    const int tid = threadIdx.x;
    const int bm = blockIdx.y * 64;
    const int bn = blockIdx.x * 64;
    const int tm = (tid & 15) * 4;
    const int tn = (tid >> 4) * 4;
    const int lr = tid >> 2;
    const int lk = (tid & 3) * 4;
    const float* Ap = A + (long)(bm + lr) * lda + lk;
    const float* Wp = W + (long)(bn + lr) * ldw + lk;
    const bool wv_ok = (bn + lr) < N;
    float acc[4][4];
    #pragma unroll
    for (int i = 0; i < 4; i++)
        #pragma unroll
        for (int j = 0; j < 4; j++) acc[i][j] = 0.f;

    for (int k0 = 0; k0 < K; k0 += 16) {
        float4 av = *(const float4*)(Ap + k0);
        float4 wv = wv_ok ? *(const float4*)(Wp + k0) : make_float4(0.f, 0.f, 0.f, 0.f);
        Asm[lk + 0][lr] = av.x; Asm[lk + 1][lr] = av.y;
        Asm[lk + 2][lr] = av.z; Asm[lk + 3][lr] = av.w;
        Wsm[lk + 0][lr] = wv.x; Wsm[lk + 1][lr] = wv.y;
        Wsm[lk + 2][lr] = wv.z; Wsm[lk + 3][lr] = wv.w;
        __syncthreads();
        #pragma unroll
        for (int k = 0; k < 16; k++) {
            float4 a = *(const float4*)&Asm[k][tm];
            float4 w = *(const float4*)&Wsm[k][tn];
            acc[0][0] += a.x * w.x; acc[0][1] += a.x * w.y; acc[0][2] += a.x * w.z; acc[0][3] += a.x * w.w;
            acc[1][0] += a.y * w.x; acc[1][1] += a.y * w.y; acc[1][2] += a.y * w.z; acc[1][3] += a.y * w.w;
            acc[2][0] += a.z * w.x; acc[2][1] += a.z * w.y; acc[2][2] += a.z * w.z; acc[2][3] += a.z * w.w;
            acc[3][0] += a.w * w.x; acc[3][1] += a.w * w.y; acc[3][2] += a.w * w.z; acc[3][3] += a.w * w.w;
        }
        __syncthreads();
    }
    #pragma unroll
    for (int i = 0; i < 4; i++) {
        long row = bm + tm + i;
        #pragma unroll
        for (int j = 0; j < 4; j++) {
            int col = bn + tn + j;
            if (col < N) {
                float v = acc[i][j];
                if (HASBIAS) v += bias[col];
                if (ACT == 1) v = gelu_exact(v);
                C[row * ldc + col] = v;
            }
        }
    }
}

// ---------------------------------------------------------------------------
// f32 -> bf16 conversion (n % 4 == 0)
// ---------------------------------------------------------------------------
__global__ __launch_bounds__(256)
void cvt_bf16(const float* __restrict__ s, bf16_t* __restrict__ d, long n)
{
    long i = ((long)blockIdx.x * 256 + threadIdx.x) * 4;
    if (i >= n) return;
    float4 v = *(const float4*)(s + i);
    d[i + 0] = __float2bfloat16(v.x);
    d[i + 1] = __float2bfloat16(v.y);
    d[i + 2] = __float2bfloat16(v.z);
    d[i + 3] = __float2bfloat16(v.w);
}

// f32 -> bf16 with zero row-padding (for in_proj weight: 2320 -> 2432 rows)
__global__ __launch_bounds__(256)
void cvt_bf16_pad(const float* __restrict__ s, bf16_t* __restrict__ d,
                  int rows_src, long total, int cols)
{
    long i = (long)blockIdx.x * 256 + threadIdx.x;
    if (i >= total) return;
    long r = i / cols;
    d[i] = __float2bfloat16(r < rows_src ? s[i] : 0.f);
}

// ---------------------------------------------------------------------------
// Causal depthwise conv (width 4) + SiLU; reads bf16 zx, writes bf16 xBC.
// ---------------------------------------------------------------------------
__global__ __launch_bounds__(256)
void conv_silu_kernel(const bf16_t* __restrict__ zx, const float* __restrict__ cw,
                      const float* __restrict__ cb, bf16_t* __restrict__ xBC, long count)
{
    long idx = (long)blockIdx.x * 256 + threadIdx.x;
    if (idx >= count) return;
    int c = (int)(idx % CDIM);
    long t = idx / CDIM;
    int s = (int)(t % S);
    float v = cb[c];
    #pragma unroll
    for (int k = 0; k < 4; k++) {
        int sp = s + k - 3;
        if (sp >= 0) v += __bfloat162float(zx[(t + k - 3) * DIP + DI + c]) * cw[c * 4 + k];
    }
    v = v / (1.f + __expf(-v));
    xBC[idx] = __float2bfloat16(v);
}

__global__ __launch_bounds__(256)
void dt_kernel(const float* __restrict__ raw, const float* __restrict__ dt_bias,
               float* __restrict__ dts, long count)
{
    long idx = (long)blockIdx.x * 256 + threadIdx.x;
    if (idx >= count) return;
    float x = raw[idx] + dt_bias[idx & 15];
    dts[idx] = (x > 20.f) ? x : log1pf(__expf(x));
}

// ---------------------------------------------------------------------------
// Intra-chunk SSD: one block per (b_local,c,h). bid = b*256 + c*16 + h.
// ---------------------------------------------------------------------------
__global__ __launch_bounds__(256)
void ssd_intra(const bf16_t* __restrict__ xBC, const float* __restrict__ dts,
               const float* __restrict__ G, const float* __restrict__ A_log,
               const float* __restrict__ D_head,
               float* __restrict__ y, float* __restrict__ statesT,
               float* __restrict__ acs_all, float* __restrict__ cdlog)
{
    const int bid = blockIdx.x;
    const int h = bid & 15;
    const int c = (bid >> 4) & 15;
    const int b = bid >> 8;
    const int tid = threadIdx.x;
    __shared__ float dtv[128];
    __shared__ float acs[128];
    __shared__ __align__(16) float Xs[128][64];
    const long t0 = (long)b * S + (long)c * CH;
    const float Ah = -__expf(A_log[h]);

    if (tid < 128) {
        float d = dts[(t0 + tid) * NH + h];
        dtv[tid] = d;
        acs[tid] = d * Ah;
    }
    __syncthreads();
    for (int off = 1; off < 128; off <<= 1) {
        float add = 0.f;
        if (tid < 128 && tid >= off) add = acs[tid - off];
        __syncthreads();
        if (tid < 128 && tid >= off) acs[tid] += add;
        __syncthreads();
    }
    for (int i = tid; i < 128 * 64; i += 256) {
        int r = i >> 6, p = i & 63;
        Xs[r][p] = __bfloat162float(xBC[(t0 + r) * CDIM + h * HD + p]);
    }
    __syncthreads();
    if (tid < 128) acs_all[(long)bid * 128 + tid] = acs[tid];
    if (tid == 0) cdlog[bid] = acs[127];

    const int r = tid >> 1;
    const int p0 = (tid & 1) * 32;
    const float er = acs[r];
    const float el = acs[127];
    const float* Grow = G + ((long)(b * NC + c) * 128 + r) * 128;

    float acc[32];
    #pragma unroll
    for (int q = 0; q < 32; q++) acc[q] = 0.f;
    for (int j = 0; j <= r; j++) {
        float w = Grow[j] * __expf(er - acs[j]) * dtv[j];
        #pragma unroll
        for (int q = 0; q < 32; q++) acc[q] += w * Xs[j][p0 + q];
    }
    {
        const float Dh = D_head[h];
        long base = (t0 + r) * DI + h * HD + p0;
        #pragma unroll
        for (int q = 0; q < 32; q++) y[base + q] = acc[q] + Dh * Xs[r][p0 + q];
    }
    const int n = r;
    #pragma unroll
    for (int q = 0; q < 32; q++) acc[q] = 0.f;
    for (int j = 0; j < 128; j++) {
        float w = __bfloat162float(xBC[(t0 + j) * CDIM + DI + n]) * __expf(el - acs[j]) * dtv[j];
        #pragma unroll
        for (int q = 0; q < 32; q++) acc[q] += w * Xs[j][p0 + q];
    }
    long sbase = (long)bid * 8192 + (long)n * 64 + p0;
    #pragma unroll
    for (int q = 0; q < 32; q++) statesT[sbase + q] = acc[q];
}

// ---------------------------------------------------------------------------
__global__ __launch_bounds__(256)
void ssd_scan(float* __restrict__ statesT, const float* __restrict__ cdlog)
{
    const int h = blockIdx.x & 15;
    const int b = blockIdx.x >> 4;
    const int tid = threadIdx.x;
    float prev[32];
    #pragma unroll
    for (int q = 0; q < 32; q++) prev[q] = 0.f;
    for (int c = 0; c < NC; c++) {
        int bc = (b * NC + c) * NH + h;
        float cd = __expf(cdlog[bc]);
        long base = (long)bc * 8192;
        #pragma unroll
        for (int q = 0; q < 32; q++) {
            long idx = base + (long)q * 256 + tid;
            float st = statesT[idx];
            statesT[idx] = prev[q];
            prev[q] = cd * prev[q] + st;
        }
    }
}

// ---------------------------------------------------------------------------
__global__ __launch_bounds__(256)
void ssd_off(const bf16_t* __restrict__ xBC, const float* __restrict__ prevT,
             const float* __restrict__ acs_all, float* __restrict__ y)
{
    const int bid = blockIdx.x;
    const int h = bid & 15;
    const int c = (bid >> 4) & 15;
    const int b = bid >> 8;
    const int tid = threadIdx.x;
    __shared__ __align__(16) float Ps[128][64];
    __shared__ float acs[128];
    const long t0 = (long)b * S + (long)c * CH;
    for (int i = tid; i < 8192; i += 256) Ps[i >> 6][i & 63] = prevT[(long)bid * 8192 + i];
    if (tid < 128) acs[tid] = acs_all[(long)bid * 128 + tid];
    __syncthreads();
    const int r = tid >> 1;
    const int p0 = (tid & 1) * 32;
    const bf16_t* Crow = xBC + (t0 + r) * CDIM + DI + DSTATE;
    float acc[32];
    #pragma unroll
    for (int q = 0; q < 32; q++) acc[q] = 0.f;
    for (int n = 0; n < 128; n++) {
        float w = __bfloat162float(Crow[n]);
        #pragma unroll
        for (int q = 0; q < 32; q++) acc[q] += w * Ps[n][p0 + q];
    }
    float e = __expf(acs[r]);
    long base = (t0 + r) * DI + h * HD + p0;
    #pragma unroll
    for (int q = 0; q < 32; q++) y[base + q] += e * acc[q];
}

// ---------------------------------------------------------------------------
// Gated RMSNorm: yn(bf16) = (y*silu(z)) * rsqrt(mean(sq)+eps) * norm_w
// ---------------------------------------------------------------------------
__global__ __launch_bounds__(256)
void gated_rms(const float* __restrict__ y, const bf16_t* __restrict__ zx,
               const float* __restrict__ norm_w, bf16_t* __restrict__ yn)
{
    const long t = blockIdx.x;
    const int tid = threadIdx.x;
    float g[4];
    float ss = 0.f, dummy = 0.f;
    #pragma unroll
    for (int q = 0; q < 4; q++) {
        int d = tid + q * 256;
        float zv = __bfloat162float(zx[t * DIP + d]);
        float yv = y[t * DI + d];
        float gv = yv * (zv / (1.f + __expf(-zv)));
        g[q] = gv;
        ss += gv * gv;
    }
    block_sum2(ss, dummy);
    float scale = rsqrtf(ss * (1.f / DI) + EPS);
    #pragma unroll
    for (int q = 0; q < 4; q++) {
        int d = tid + q * 256;
        yn[t * DI + d] = __float2bfloat16(g[q] * scale * norm_w[d]);
    }
}

// ---------------------------------------------------------------------------
// out = LayerNorm(x + r); writes both f32 and bf16 copies.
// ---------------------------------------------------------------------------
__global__ __launch_bounds__(256)
void add_ln(const float* __restrict__ x, const float* __restrict__ r,
            const float* __restrict__ w, const float* __restrict__ bpar,
            float* __restrict__ o32, bf16_t* __restrict__ o16)
{
    const long t = blockIdx.x;
    const int tid = threadIdx.x;
    float v[2];
    float s = 0.f, s2 = 0.f;
    #pragma unroll
    for (int q = 0; q < 2; q++) {
        int d = tid + q * 256;
        float vv = x[t * DM + d] + r[t * DM + d];
        v[q] = vv;
        s += vv;
        s2 += vv * vv;
    }
    block_sum2(s, s2);
    float mean = s * (1.f / DM);
    float var = s2 * (1.f / DM) - mean * mean;
    float inv = rsqrtf(var + EPS);
    #pragma unroll
    for (int q = 0; q < 2; q++) {
        int d = tid + q * 256;
        float o = (v[q] - mean) * inv * w[d] + bpar[d];
        o32[t * DM + d] = o;
        o16[t * DM + d] = __float2bfloat16(o);
    }
}

// ---------------------------------------------------------------------------

extern "C" void kernel_launch(void* const* d_in, const int* in_sizes, int n_in,
                              void* d_out, int out_size, void* d_ws, size_t ws_size,
                              hipStream_t stream)
{
    const float* tgt       = (const float*)d_in[0];
    const float* in_proj_w = (const float*)d_in[5];
    const float* conv_w    = (const float*)d_in[6];
    const float* conv_b    = (const float*)d_in[7];
    const float* dt_bias   = (const float*)d_in[8];
    const float* A_log     = (const float*)d_in[9];
    const float* D_head    = (const float*)d_in[10];
    const float* norm_w    = (const float*)d_in[11];
    const float* out_proj_w= (const float*)d_in[12];
    const float* norm1_w   = (const float*)d_in[13];
    const float* norm1_b   = (const float*)d_in[14];
    const float* w1        = (const float*)d_in[15];
    const float* b1        = (const float*)d_in[16];
    const float* w2        = (const float*)d_in[17];
    const float* b2        = (const float*)d_in[18];
    const float* norm3_w   = (const float*)d_in[19];
    const float* norm3_b   = (const float*)d_in[20];
    float* out = (float*)d_out;

    float* ws = (float*)d_ws;

    // Weight arena (bf16), converted once per call (floats of storage):
    const size_t SZ_INW  = (size_t)DIPP * DM / 2;   // 622,592
    const size_t SZ_OUTW = (size_t)DM * DI / 2;     // 262,144
    const size_t SZ_W1   = (size_t)FF * DM / 2;     // 524,288
    const size_t SZ_W2   = (size_t)DM * FF / 2;     // 524,288
    size_t wo = 0;
    bf16_t* inW  = (bf16_t*)(ws + wo); wo += SZ_INW;
    bf16_t* outW = (bf16_t*)(ws + wo); wo += SZ_OUTW;
    bf16_t* w1b  = (bf16_t*)(ws + wo); wo += SZ_W1;
    bf16_t* w2b  = (bf16_t*)(ws + wo); wo += SZ_W2;
    const size_t WB = wo;                           // 1,933,312 floats

    // Per-batch arena (floats):
    const size_t PB = (size_t)S * DM / 2            // tgt_bf
                    + (size_t)S * DIP / 2           // zx_bf
                    + (size_t)S * NH                // dts_raw
                    + (size_t)S * NH                // dts
                    + (size_t)S * CDIM / 2          // xBC_bf
                    + (size_t)NC * 128 * 128        // G
                    + (size_t)NC * NH * 128         // acs
                    + (size_t)NC * NH               // cdl
                    + (size_t)S * DI                // y
                    + (size_t)S * DI;               // statesT
    int NB = 0;
    for (int nb = 8; nb >= 1; nb >>= 1) {
        if (ws_size >= (WB + (size_t)nb * PB) * sizeof(float)) { NB = nb; break; }
    }
    if (NB == 0) return;

    // ---- weight conversions (identical every call; graph-safe) ----
    {
        long n = (long)DIPP * DM;
        cvt_bf16_pad<<<(n + 255) / 256, 256, 0, stream>>>(in_proj_w, inW, DIP, n, DM);
        n = (long)DM * DI;
        cvt_bf16<<<(n / 4 + 255) / 256, 256, 0, stream>>>(out_proj_w, outW, n);
        n = (long)FF * DM;
        cvt_bf16<<<(n / 4 + 255) / 256, 256, 0, stream>>>(w1, w1b, n);
        n = (long)DM * FF;
        cvt_bf16<<<(n / 4 + 255) / 256, 256, 0, stream>>>(w2, w2b, n);
    }

    for (int b0 = 0; b0 < BB; b0 += NB) {
        const long Tg = (long)NB * S;
        size_t o = WB;
        bf16_t* tgt_bf = (bf16_t*)(ws + o); o += (size_t)Tg * DM / 2;
        bf16_t* zx     = (bf16_t*)(ws + o); o += (size_t)Tg * DIP / 2;
        float*  dts_raw= ws + o;            o += (size_t)Tg * NH;
        float*  dts    = ws + o;            o += (size_t)Tg * NH;
        bf16_t* xBC    = (bf16_t*)(ws + o); o += (size_t)Tg * CDIM / 2;
        float*  G      = ws + o;            o += (size_t)NB * NC * 128 * 128;
        float*  acs    = ws + o;            o += (size_t)NB * NC * NH * 128;
        float*  cdl    = ws + o;            o += (size_t)NB * NC * NH;
        float*  ybuf   = ws + o;            o += (size_t)Tg * DI;
        float*  st     = ws + o;            o += (size_t)Tg * DI;

        // lifetime-disjoint aliases
        bf16_t* yn  = (bf16_t*)st;                       // after ssd_off
        float*  t2  = ybuf;                              // after gated_rms
        float*  tb  = (float*)zx;                        // t f32, after gated_rms
        bf16_t* tbb = (bf16_t*)(((float*)zx) + Tg * DM); // t bf16 alongside
        bf16_t* h1  = (bf16_t*)ybuf;                     // after add_ln1 (T*FF bf16 = T*DI f32)
        float*  fb  = (float*)xBC;                       // after ssd_off
        bf16_t* dummy16 = tbb;                           // step-13 bf16 sink (t_bf dead)

        const float* tgt_g = tgt + (long)b0 * S * DM;
        float* out_g = out + (long)b0 * S * DM;

        // 1. tgt -> bf16
        cvt_bf16<<<((Tg * DM) / 4 + 255) / 256, 256, 0, stream>>>(tgt_g, tgt_bf, Tg * DM);
        // 2. in_proj (bf16 MFMA): zx = tgt_bf @ inW^T   [N=2320 padded 2432]
        mfma_gemm<0, false, true><<<dim3(DIPP / 128, Tg / 128, 1), 256, 0, stream>>>(
            tgt_bf, inW, nullptr, zx, DIP, DM, DM, DM, DIP, 0, 0, 0);
        // 3. dt projection (f32): dts_raw = tgt_g @ in_proj_w[dt rows]^T
        gemm_kernel<0, false><<<dim3(1, Tg / 64, 1), 256, 0, stream>>>(
            tgt_g, in_proj_w + (long)(DI + CDIM) * DM, nullptr, dts_raw,
            Tg, NH, DM, DM, DM, NH, 0, 0, 0);
        // 4. softplus(dt + bias)
        dt_kernel<<<(Tg * NH) / 256, 256, 0, stream>>>(dts_raw, dt_bias, dts, Tg * NH);
        // 5. conv + silu
        conv_silu_kernel<<<(Tg * CDIM) / 256, 256, 0, stream>>>(zx, conv_w, conv_b, xBC, Tg * CDIM);
        // 6. per-chunk G = C @ B^T (bf16 MFMA, batched over NB*NC chunks)
        mfma_gemm<0, false, false><<<dim3(1, 1, NB * NC), 256, 0, stream>>>(
            xBC + DI + DSTATE, xBC + DI, nullptr, G,
            128, 128, CDIM, CDIM, 128,
            (long)CH * CDIM, (long)CH * CDIM, (long)128 * 128);
        // 7. intra-chunk SSD
        ssd_intra<<<NB * NC * NH, 256, 0, stream>>>(xBC, dts, G, A_log, D_head, ybuf, st, acs, cdl);
        // 8. inter-chunk scan
        ssd_scan<<<NB * NH, 256, 0, stream>>>(st, cdl);
        // 9. off-chunk contribution
        ssd_off<<<NB * NC * NH, 256, 0, stream>>>(xBC, st, acs, ybuf);
        // 10. gated RMSNorm -> yn (bf16, overwrites statesT)
        gated_rms<<<Tg, 256, 0, stream>>>(ybuf, zx, norm_w, yn);
        // 11. out_proj (bf16 MFMA): t2 = yn @ outW^T
        mfma_gemm<0, false, false><<<dim3(DM / 128, Tg / 128, 1), 256, 0, stream>>>(
            yn, outW, nullptr, t2, DM, DI, DI, DI, DM, 0, 0, 0);
        // 12. t = LN(tgt + t2)  (f32 + bf16)
        add_ln<<<Tg, 256, 0, stream>>>(tgt_g, t2, norm1_w, norm1_b, tb, tbb);
        // 13. h1 = gelu(t @ w1^T + b1) (bf16 MFMA, bf16 out)
        mfma_gemm<1, true, true><<<dim3(FF / 128, Tg / 128, 1), 256, 0, stream>>>(
            tbb, w1b, b1, h1, FF, DM, DM, DM, FF, 0, 0, 0);
        // 14. f = h1 @ w2^T + b2 (bf16 MFMA)
        mfma_gemm<0, true, false><<<dim3(DM / 128, Tg / 128, 1), 256, 0, stream>>>(
            h1, w2b, b2, fb, DM, FF, FF, FF, DM, 0, 0, 0);
        // 15. out = LN(t + f)
        add_ln<<<Tg, 256, 0, stream>>>(tb, fb, norm3_w, norm3_b, out_g, dummy16);
    }
}

// Round 4
// 1077.605 us; speedup vs baseline: 2.2417x; 1.0639x over previous
//
#include <hip/hip_runtime.h>
#include <hip/hip_bf16.h>
#include <math.h>

// ---------------------------------------------------------------------------
// Mamba2 layer (round 3): MFMA GEMM rewritten as register-staged + LDS
// double-buffered pipeline (ONE barrier per K-iter; global loads issued
// before the barrier, consumed by ds_write after the MFMA phase — latency
// overlapped by compute instead of drained at the barrier).
// BM=64 tile variant for the skinny-N (512) GEMMs to raise block count.
// dt path stays f32; SSD/LN internals f32. Adaptive batch-group loop.
// ---------------------------------------------------------------------------

namespace {
constexpr int BB = 8;
constexpr int S = 2048;
constexpr int DM = 512;
constexpr int DIP = 2320;        // in_proj output dim
constexpr int DIPP = 2432;       // padded to 19*128 for MFMA tiles
constexpr int DI = 1024;         // d_inner
constexpr int CDIM = 1280;       // conv dim
constexpr int NH = 16;
constexpr int HD = 64;
constexpr int DSTATE = 128;
constexpr int CH = 128;          // chunk length
constexpr int NC = S / CH;       // 16 chunks
constexpr int FF = 2048;
constexpr float EPS = 1e-5f;
}

using bf16_t = __hip_bfloat16;
typedef __attribute__((ext_vector_type(8))) short short8;   // 8 bf16 = 4 VGPR
typedef __attribute__((ext_vector_type(4))) float f32x4;

__device__ __forceinline__ float gelu_exact(float x) {
    return 0.5f * x * (1.0f + erff(x * 0.7071067811865476f));
}

__device__ __forceinline__ void block_sum2(float& a, float& b) {
    #pragma unroll
    for (int o = 32; o > 0; o >>= 1) {
        a += __shfl_down(a, o, 64);
        b += __shfl_down(b, o, 64);
    }
    __shared__ float sa[4], sb[4];
    int w = threadIdx.x >> 6;
    if ((threadIdx.x & 63) == 0) { sa[w] = a; sb[w] = b; }
    __syncthreads();
    a = sa[0] + sa[1] + sa[2] + sa[3];
    b = sb[0] + sb[1] + sb[2] + sb[3];
}

// ---------------------------------------------------------------------------
// bf16 MFMA GEMM, pipelined: C[m,n] = act(sum_k A[m,k]*W[n,k] + bias[n])
// A:[M,K] bf16 rm, W:[N,K] bf16 rm (B^T form), C f32/bf16. BN=128 fixed,
// BM template (128: 4 waves x 64x64; 64: 4 waves x 64x32). BK=32.
// Per K-iter: issue next-tile global->VGPR loads, ONE barrier, ds_read+MFMA
// from buf[cur], ds_write staged regs to buf[nxt]. Requires M%BM==0, K%32==0,
// W padded to grid.x*128 rows (loads in-bounds); store guarded by N.
// ---------------------------------------------------------------------------
template <int BM, int ACT, bool HASBIAS, bool OUTBF>
__global__ __launch_bounds__(256)
void mfma_gemm(const bf16_t* __restrict__ A, const bf16_t* __restrict__ W,
               const float* __restrict__ bias, void* __restrict__ Cout,
               int N, int K, int lda, int ldw, int ldc,
               long batchA, long batchW, long batchC)
{
    A += (long)blockIdx.z * batchA;
    W += (long)blockIdx.z * batchW;
    constexpr int ACH = BM / 64;               // A chunks per thread (2 or 1)
    constexpr int NJ = (BM == 128) ? 4 : 2;    // N sub-tiles per wave
    __shared__ bf16_t As[2][BM * 32];
    __shared__ bf16_t Ws[2][4096];
    const int tid = threadIdx.x;
    const int lane = tid & 63;
    const int wave = tid >> 6;
    const long bm = (long)blockIdx.y * BM;
    const int bn = blockIdx.x * 128;

    // staging geometry
    const int rA = tid & (BM - 1);
    const int qA = tid / BM;                   // BM=128: 0..1 ; BM=64: 0..3
    const int rW = tid & 127;
    const int qW = tid >> 7;
    const bf16_t* Ag = A + (bm + rA) * (long)lda + qA * 8;
    const bf16_t* Wg = W + ((long)bn + rW) * (long)ldw + qW * 8;
    const int laoff0 = (qA * BM + rA) * 8;
    const int laoff1 = ((qA + 2) * BM + rA) * 8;   // only used when ACH==2
    const int lwoff0 = (qW * 128 + rW) * 8;
    const int lwoff1 = ((qW + 2) * 128 + rW) * 8;

    const int kq = lane >> 4;
    const int lr = lane & 15;
    const int wm = (BM == 128) ? (wave & 1) * 64 : 0;
    const int wn = (BM == 128) ? (wave >> 1) * 64 : wave * 32;

    f32x4 acc[4][NJ];
    #pragma unroll
    for (int i = 0; i < 4; i++)
        #pragma unroll
        for (int j = 0; j < NJ; j++) acc[i][j] = (f32x4){0.f, 0.f, 0.f, 0.f};

    short8 ra0, ra1, rw0, rw1;
    ra0 = *(const short8*)Ag;
    if (ACH == 2) ra1 = *(const short8*)(Ag + 16);
    rw0 = *(const short8*)Wg;
    rw1 = *(const short8*)(Wg + 16);
    // prologue: stage tile 0 into buf 0
    *(short8*)&As[0][laoff0] = ra0;
    if (ACH == 2) *(short8*)&As[0][laoff1] = ra1;
    *(short8*)&Ws[0][lwoff0] = rw0;
    *(short8*)&Ws[0][lwoff1] = rw1;

    const int nt = K / 32;
    for (int t = 0; t < nt; t++) {
        const int cur = t & 1, nxt = cur ^ 1;
        if (t + 1 < nt) {
            const int ko = (t + 1) * 32;
            ra0 = *(const short8*)(Ag + ko);
            if (ACH == 2) ra1 = *(const short8*)(Ag + ko + 16);
            rw0 = *(const short8*)(Wg + ko);
            rw1 = *(const short8*)(Wg + ko + 16);
        }
        __syncthreads();   // buf[cur] writes visible; all prior reads complete
        short8 af[4], bfr[NJ];
        #pragma unroll
        for (int i = 0; i < 4; i++)
            af[i] = *(const short8*)&As[cur][(kq * BM + wm + i * 16 + lr) * 8];
        #pragma unroll
        for (int j = 0; j < NJ; j++)
            bfr[j] = *(const short8*)&Ws[cur][(kq * 128 + wn + j * 16 + lr) * 8];
        #pragma unroll
        for (int i = 0; i < 4; i++)
            #pragma unroll
            for (int j = 0; j < NJ; j++)
                acc[i][j] = __builtin_amdgcn_mfma_f32_16x16x32_bf16(af[i], bfr[j], acc[i][j], 0, 0, 0);
        if (t + 1 < nt) {
            *(short8*)&As[nxt][laoff0] = ra0;
            if (ACH == 2) *(short8*)&As[nxt][laoff1] = ra1;
            *(short8*)&Ws[nxt][lwoff0] = rw0;
            *(short8*)&Ws[nxt][lwoff1] = rw1;
        }
    }

    // epilogue: C/D layout col=lane&15, row=(lane>>4)*4+reg (m89-verified)
    #pragma unroll
    for (int i = 0; i < 4; i++) {
        #pragma unroll
        for (int j = 0; j < NJ; j++) {
            int col = bn + wn + j * 16 + lr;
            if (col < N) {
                float bv = HASBIAS ? bias[col] : 0.f;
                #pragma unroll
                for (int r = 0; r < 4; r++) {
                    long row = bm + wm + i * 16 + kq * 4 + r;
                    float v = acc[i][j][r] + bv;
                    if (ACT == 1) v = gelu_exact(v);
                    if (OUTBF) ((bf16_t*)Cout)[row * (long)ldc + col + blockIdx.z * batchC] = __float2bfloat16(v);
                    else       ((float*)Cout)[row * (long)ldc + col + blockIdx.z * batchC] = v;
                }
            }
        }
    }
}

// ---------------------------------------------------------------------------
// f32 GEMM (kept for the tiny dt projection, N=16): 64x64 tile, BK=16.
// ---------------------------------------------------------------------------
template <int ACT, bool HASBIAS>
__global__ __launch_bounds__(256)
void gemm_kernel(const float* __restrict__ A, const float* __restrict__ W,
                 const float* __restrict__ bias, float* __restrict__ C,
                 int M, int N, int K, int lda, int ldw, int ldc,
                 long batchA, long batchW, long batchC)
{
    A += (long)blockIdx.z * batchA;
    W += (long)blockIdx.z * batchW;
    C += (long)blockIdx.z * batchC;
    __shared__ __align__(16) float Asm[16][68];
    __shared__ __align__(16) float Wsm[16][68];
    const int tid = threadIdx.x;
    const int bm = blockIdx.y * 64;
    const int bn = blockIdx.x * 64;
    const int tm = (tid & 15) * 4;
    const int tn = (tid >> 4) * 4;
    const int lr = tid >> 2;
    const int lk = (tid & 3) * 4;
    const float* Ap = A + (long)(bm + lr) * lda + lk;
    const float* Wp = W + (long)(bn + lr) * ldw + lk;
    const bool wv_ok = (bn + lr) < N;
    float acc[4][4];
    #pragma unroll
    for (int i = 0; i < 4; i++)
        #pragma unroll
        for (int j = 0; j < 4; j++) acc[i][j] = 0.f;

    for (int k0 = 0; k0 < K; k0 += 16) {
        float4 av = *(const float4*)(Ap + k0);
        float4 wv = wv_ok ? *(const float4*)(Wp + k0) : make_float4(0.f, 0.f, 0.f, 0.f);
        Asm[lk + 0][lr] = av.x; Asm[lk + 1][lr] = av.y;
        Asm[lk + 2][lr] = av.z; Asm[lk + 3][lr] = av.w;
        Wsm[lk + 0][lr] = wv.x; Wsm[lk + 1][lr] = wv.y;
        Wsm[lk + 2][lr] = wv.z; Wsm[lk + 3][lr] = wv.w;
        __syncthreads();
        #pragma unroll
        for (int k = 0; k < 16; k++) {
            float4 a = *(const float4*)&Asm[k][tm];
            float4 w = *(const float4*)&Wsm[k][tn];
            acc[0][0] += a.x * w.x; acc[0][1] += a.x * w.y; acc[0][2] += a.x * w.z; acc[0][3] += a.x * w.w;
            acc[1][0] += a.y * w.x; acc[1][1] += a.y * w.y; acc[1][2] += a.y * w.z; acc[1][3] += a.y * w.w;
            acc[2][0] += a.z * w.x; acc[2][1] += a.z * w.y; acc[2][2] += a.z * w.z; acc[2][3] += a.z * w.w;
            acc[3][0] += a.w * w.x; acc[3][1] += a.w * w.y; acc[3][2] += a.w * w.z; acc[3][3] += a.w * w.w;
        }
        __syncthreads();
    }
    #pragma unroll
    for (int i = 0; i < 4; i++) {
        long row = bm + tm + i;
        #pragma unroll
        for (int j = 0; j < 4; j++) {
            int col = bn + tn + j;
            if (col < N) {
                float v = acc[i][j];
                if (HASBIAS) v += bias[col];
                if (ACT == 1) v = gelu_exact(v);
                C[row * ldc + col] = v;
            }
        }
    }
}

// ---------------------------------------------------------------------------
__global__ __launch_bounds__(256)
void cvt_bf16(const float* __restrict__ s, bf16_t* __restrict__ d, long n)
{
    long i = ((long)blockIdx.x * 256 + threadIdx.x) * 4;
    if (i >= n) return;
    float4 v = *(const float4*)(s + i);
    d[i + 0] = __float2bfloat16(v.x);
    d[i + 1] = __float2bfloat16(v.y);
    d[i + 2] = __float2bfloat16(v.z);
    d[i + 3] = __float2bfloat16(v.w);
}

__global__ __launch_bounds__(256)
void cvt_bf16_pad(const float* __restrict__ s, bf16_t* __restrict__ d,
                  int rows_src, long total, int cols)
{
    long i = (long)blockIdx.x * 256 + threadIdx.x;
    if (i >= total) return;
    long r = i / cols;
    d[i] = __float2bfloat16(r < rows_src ? s[i] : 0.f);
}

// ---------------------------------------------------------------------------
__global__ __launch_bounds__(256)
void conv_silu_kernel(const bf16_t* __restrict__ zx, const float* __restrict__ cw,
                      const float* __restrict__ cb, bf16_t* __restrict__ xBC, long count)
{
    long idx = (long)blockIdx.x * 256 + threadIdx.x;
    if (idx >= count) return;
    int c = (int)(idx % CDIM);
    long t = idx / CDIM;
    int s = (int)(t % S);
    float v = cb[c];
    #pragma unroll
    for (int k = 0; k < 4; k++) {
        int sp = s + k - 3;
        if (sp >= 0) v += __bfloat162float(zx[(t + k - 3) * DIP + DI + c]) * cw[c * 4 + k];
    }
    v = v / (1.f + __expf(-v));
    xBC[idx] = __float2bfloat16(v);
}

__global__ __launch_bounds__(256)
void dt_kernel(const float* __restrict__ raw, const float* __restrict__ dt_bias,
               float* __restrict__ dts, long count)
{
    long idx = (long)blockIdx.x * 256 + threadIdx.x;
    if (idx >= count) return;
    float x = raw[idx] + dt_bias[idx & 15];
    dts[idx] = (x > 20.f) ? x : log1pf(__expf(x));
}

// ---------------------------------------------------------------------------
__global__ __launch_bounds__(256)
void ssd_intra(const bf16_t* __restrict__ xBC, const float* __restrict__ dts,
               const float* __restrict__ G, const float* __restrict__ A_log,
               const float* __restrict__ D_head,
               float* __restrict__ y, float* __restrict__ statesT,
               float* __restrict__ acs_all, float* __restrict__ cdlog)
{
    const int bid = blockIdx.x;
    const int h = bid & 15;
    const int c = (bid >> 4) & 15;
    const int b = bid >> 8;
    const int tid = threadIdx.x;
    __shared__ float dtv[128];
    __shared__ float acs[128];
    __shared__ __align__(16) float Xs[128][64];
    const long t0 = (long)b * S + (long)c * CH;
    const float Ah = -__expf(A_log[h]);

    if (tid < 128) {
        float d = dts[(t0 + tid) * NH + h];
        dtv[tid] = d;
        acs[tid] = d * Ah;
    }
    __syncthreads();
    for (int off = 1; off < 128; off <<= 1) {
        float add = 0.f;
        if (tid < 128 && tid >= off) add = acs[tid - off];
        __syncthreads();
        if (tid < 128 && tid >= off) acs[tid] += add;
        __syncthreads();
    }
    for (int i = tid; i < 128 * 64; i += 256) {
        int r = i >> 6, p = i & 63;
        Xs[r][p] = __bfloat162float(xBC[(t0 + r) * CDIM + h * HD + p]);
    }
    __syncthreads();
    if (tid < 128) acs_all[(long)bid * 128 + tid] = acs[tid];
    if (tid == 0) cdlog[bid] = acs[127];

    const int r = tid >> 1;
    const int p0 = (tid & 1) * 32;
    const float er = acs[r];
    const float el = acs[127];
    const float* Grow = G + ((long)(b * NC + c) * 128 + r) * 128;

    float acc[32];
    #pragma unroll
    for (int q = 0; q < 32; q++) acc[q] = 0.f;
    for (int j = 0; j <= r; j++) {
        float w = Grow[j] * __expf(er - acs[j]) * dtv[j];
        #pragma unroll
        for (int q = 0; q < 32; q++) acc[q] += w * Xs[j][p0 + q];
    }
    {
        const float Dh = D_head[h];
        long base = (t0 + r) * DI + h * HD + p0;
        #pragma unroll
        for (int q = 0; q < 32; q++) y[base + q] = acc[q] + Dh * Xs[r][p0 + q];
    }
    const int n = r;
    #pragma unroll
    for (int q = 0; q < 32; q++) acc[q] = 0.f;
    for (int j = 0; j < 128; j++) {
        float w = __bfloat162float(xBC[(t0 + j) * CDIM + DI + n]) * __expf(el - acs[j]) * dtv[j];
        #pragma unroll
        for (int q = 0; q < 32; q++) acc[q] += w * Xs[j][p0 + q];
    }
    long sbase = (long)bid * 8192 + (long)n * 64 + p0;
    #pragma unroll
    for (int q = 0; q < 32; q++) statesT[sbase + q] = acc[q];
}

// ---------------------------------------------------------------------------
__global__ __launch_bounds__(256)
void ssd_scan(float* __restrict__ statesT, const float* __restrict__ cdlog)
{
    const int h = blockIdx.x & 15;
    const int b = blockIdx.x >> 4;
    const int tid = threadIdx.x;
    float prev[32];
    #pragma unroll
    for (int q = 0; q < 32; q++) prev[q] = 0.f;
    for (int c = 0; c < NC; c++) {
        int bc = (b * NC + c) * NH + h;
        float cd = __expf(cdlog[bc]);
        long base = (long)bc * 8192;
        #pragma unroll
        for (int q = 0; q < 32; q++) {
            long idx = base + (long)q * 256 + tid;
            float st = statesT[idx];
            statesT[idx] = prev[q];
            prev[q] = cd * prev[q] + st;
        }
    }
}

// ---------------------------------------------------------------------------
__global__ __launch_bounds__(256)
void ssd_off(const bf16_t* __restrict__ xBC, const float* __restrict__ prevT,
             const float* __restrict__ acs_all, float* __restrict__ y)
{
    const int bid = blockIdx.x;
    const int h = bid & 15;
    const int c = (bid >> 4) & 15;
    const int b = bid >> 8;
    const int tid = threadIdx.x;
    __shared__ __align__(16) float Ps[128][64];
    __shared__ float acs[128];
    const long t0 = (long)b * S + (long)c * CH;
    for (int i = tid; i < 8192; i += 256) Ps[i >> 6][i & 63] = prevT[(long)bid * 8192 + i];
    if (tid < 128) acs[tid] = acs_all[(long)bid * 128 + tid];
    __syncthreads();
    const int r = tid >> 1;
    const int p0 = (tid & 1) * 32;
    const bf16_t* Crow = xBC + (t0 + r) * CDIM + DI + DSTATE;
    float acc[32];
    #pragma unroll
    for (int q = 0; q < 32; q++) acc[q] = 0.f;
    for (int n = 0; n < 128; n++) {
        float w = __bfloat162float(Crow[n]);
        #pragma unroll
        for (int q = 0; q < 32; q++) acc[q] += w * Ps[n][p0 + q];
    }
    float e = __expf(acs[r]);
    long base = (t0 + r) * DI + h * HD + p0;
    #pragma unroll
    for (int q = 0; q < 32; q++) y[base + q] += e * acc[q];
}

// ---------------------------------------------------------------------------
__global__ __launch_bounds__(256)
void gated_rms(const float* __restrict__ y, const bf16_t* __restrict__ zx,
               const float* __restrict__ norm_w, bf16_t* __restrict__ yn)
{
    const long t = blockIdx.x;
    const int tid = threadIdx.x;
    float g[4];
    float ss = 0.f, dummy = 0.f;
    #pragma unroll
    for (int q = 0; q < 4; q++) {
        int d = tid + q * 256;
        float zv = __bfloat162float(zx[t * DIP + d]);
        float yv = y[t * DI + d];
        float gv = yv * (zv / (1.f + __expf(-zv)));
        g[q] = gv;
        ss += gv * gv;
    }
    block_sum2(ss, dummy);
    float scale = rsqrtf(ss * (1.f / DI) + EPS);
    #pragma unroll
    for (int q = 0; q < 4; q++) {
        int d = tid + q * 256;
        yn[t * DI + d] = __float2bfloat16(g[q] * scale * norm_w[d]);
    }
}

// ---------------------------------------------------------------------------
__global__ __launch_bounds__(256)
void add_ln(const float* __restrict__ x, const float* __restrict__ r,
            const float* __restrict__ w, const float* __restrict__ bpar,
            float* __restrict__ o32, bf16_t* __restrict__ o16)
{
    const long t = blockIdx.x;
    const int tid = threadIdx.x;
    float v[2];
    float s = 0.f, s2 = 0.f;
    #pragma unroll
    for (int q = 0; q < 2; q++) {
        int d = tid + q * 256;
        float vv = x[t * DM + d] + r[t * DM + d];
        v[q] = vv;
        s += vv;
        s2 += vv * vv;
    }
    block_sum2(s, s2);
    float mean = s * (1.f / DM);
    float var = s2 * (1.f / DM) - mean * mean;
    float inv = rsqrtf(var + EPS);
    #pragma unroll
    for (int q = 0; q < 2; q++) {
        int d = tid + q * 256;
        float o = (v[q] - mean) * inv * w[d] + bpar[d];
        o32[t * DM + d] = o;
        o16[t * DM + d] = __float2bfloat16(o);
    }
}

// ---------------------------------------------------------------------------

extern "C" void kernel_launch(void* const* d_in, const int* in_sizes, int n_in,
                              void* d_out, int out_size, void* d_ws, size_t ws_size,
                              hipStream_t stream)
{
    const float* tgt       = (const float*)d_in[0];
    const float* in_proj_w = (const float*)d_in[5];
    const float* conv_w    = (const float*)d_in[6];
    const float* conv_b    = (const float*)d_in[7];
    const float* dt_bias   = (const float*)d_in[8];
    const float* A_log     = (const float*)d_in[9];
    const float* D_head    = (const float*)d_in[10];
    const float* norm_w    = (const float*)d_in[11];
    const float* out_proj_w= (const float*)d_in[12];
    const float* norm1_w   = (const float*)d_in[13];
    const float* norm1_b   = (const float*)d_in[14];
    const float* w1        = (const float*)d_in[15];
    const float* b1        = (const float*)d_in[16];
    const float* w2        = (const float*)d_in[17];
    const float* b2        = (const float*)d_in[18];
    const float* norm3_w   = (const float*)d_in[19];
    const float* norm3_b   = (const float*)d_in[20];
    float* out = (float*)d_out;

    float* ws = (float*)d_ws;

    // Weight arena (bf16), converted every call (graph-safe):
    const size_t SZ_INW  = (size_t)DIPP * DM / 2;
    const size_t SZ_OUTW = (size_t)DM * DI / 2;
    const size_t SZ_W1   = (size_t)FF * DM / 2;
    const size_t SZ_W2   = (size_t)DM * FF / 2;
    size_t wo = 0;
    bf16_t* inW  = (bf16_t*)(ws + wo); wo += SZ_INW;
    bf16_t* outW = (bf16_t*)(ws + wo); wo += SZ_OUTW;
    bf16_t* w1b  = (bf16_t*)(ws + wo); wo += SZ_W1;
    bf16_t* w2b  = (bf16_t*)(ws + wo); wo += SZ_W2;
    const size_t WB = wo;

    // Per-batch arena (floats):
    const size_t PB = (size_t)S * DM / 2            // tgt_bf
                    + (size_t)S * DIP / 2           // zx_bf
                    + (size_t)S * NH                // dts_raw
                    + (size_t)S * NH                // dts
                    + (size_t)S * CDIM / 2          // xBC_bf
                    + (size_t)NC * 128 * 128        // G
                    + (size_t)NC * NH * 128         // acs
                    + (size_t)NC * NH               // cdl
                    + (size_t)S * DI                // y
                    + (size_t)S * DI;               // statesT
    int NB = 0;
    for (int nb = 8; nb >= 1; nb >>= 1) {
        if (ws_size >= (WB + (size_t)nb * PB) * sizeof(float)) { NB = nb; break; }
    }
    if (NB == 0) return;

    {
        long n = (long)DIPP * DM;
        cvt_bf16_pad<<<(n + 255) / 256, 256, 0, stream>>>(in_proj_w, inW, DIP, n, DM);
        n = (long)DM * DI;
        cvt_bf16<<<(n / 4 + 255) / 256, 256, 0, stream>>>(out_proj_w, outW, n);
        n = (long)FF * DM;
        cvt_bf16<<<(n / 4 + 255) / 256, 256, 0, stream>>>(w1, w1b, n);
        n = (long)DM * FF;
        cvt_bf16<<<(n / 4 + 255) / 256, 256, 0, stream>>>(w2, w2b, n);
    }

    for (int b0 = 0; b0 < BB; b0 += NB) {
        const long Tg = (long)NB * S;
        size_t o = WB;
        bf16_t* tgt_bf = (bf16_t*)(ws + o); o += (size_t)Tg * DM / 2;
        bf16_t* zx     = (bf16_t*)(ws + o); o += (size_t)Tg * DIP / 2;
        float*  dts_raw= ws + o;            o += (size_t)Tg * NH;
        float*  dts    = ws + o;            o += (size_t)Tg * NH;
        bf16_t* xBC    = (bf16_t*)(ws + o); o += (size_t)Tg * CDIM / 2;
        float*  G      = ws + o;            o += (size_t)NB * NC * 128 * 128;
        float*  acs    = ws + o;            o += (size_t)NB * NC * NH * 128;
        float*  cdl    = ws + o;            o += (size_t)NB * NC * NH;
        float*  ybuf   = ws + o;            o += (size_t)Tg * DI;
        float*  st     = ws + o;            o += (size_t)Tg * DI;

        // lifetime-disjoint aliases
        bf16_t* yn  = (bf16_t*)st;                       // after ssd_off
        float*  t2  = ybuf;                              // after gated_rms
        float*  tb  = (float*)zx;                        // t f32, after gated_rms
        bf16_t* tbb = (bf16_t*)(((float*)zx) + Tg * DM); // t bf16 alongside
        bf16_t* h1  = (bf16_t*)ybuf;                     // after add_ln1
        float*  fb  = (float*)xBC;                       // after ssd_off
        bf16_t* dummy16 = tbb;                           // step-15 bf16 sink

        const float* tgt_g = tgt + (long)b0 * S * DM;
        float* out_g = out + (long)b0 * S * DM;

        // 1. tgt -> bf16
        cvt_bf16<<<((Tg * DM) / 4 + 255) / 256, 256, 0, stream>>>(tgt_g, tgt_bf, Tg * DM);
        // 2. in_proj (MFMA): zx = tgt_bf @ inW^T   [N=2320 padded 2432]
        mfma_gemm<128, 0, false, true><<<dim3(DIPP / 128, Tg / 128, 1), 256, 0, stream>>>(
            tgt_bf, inW, nullptr, zx, DIP, DM, DM, DM, DIP, 0, 0, 0);
        // 3. dt projection (f32)
        gemm_kernel<0, false><<<dim3(1, Tg / 64, 1), 256, 0, stream>>>(
            tgt_g, in_proj_w + (long)(DI + CDIM) * DM, nullptr, dts_raw,
            Tg, NH, DM, DM, DM, NH, 0, 0, 0);
        // 4. softplus(dt + bias)
        dt_kernel<<<(Tg * NH) / 256, 256, 0, stream>>>(dts_raw, dt_bias, dts, Tg * NH);
        // 5. conv + silu
        conv_silu_kernel<<<(Tg * CDIM) / 256, 256, 0, stream>>>(zx, conv_w, conv_b, xBC, Tg * CDIM);
        // 6. per-chunk G = C @ B^T (MFMA, batched over NB*NC chunks)
        mfma_gemm<128, 0, false, false><<<dim3(1, 1, NB * NC), 256, 0, stream>>>(
            xBC + DI + DSTATE, xBC + DI, nullptr, G,
            128, DSTATE, CDIM, CDIM, 128,
            (long)CH * CDIM, (long)CH * CDIM, (long)128 * 128);
        // 7. intra-chunk SSD
        ssd_intra<<<NB * NC * NH, 256, 0, stream>>>(xBC, dts, G, A_log, D_head, ybuf, st, acs, cdl);
        // 8. inter-chunk scan
        ssd_scan<<<NB * NH, 256, 0, stream>>>(st, cdl);
        // 9. off-chunk contribution
        ssd_off<<<NB * NC * NH, 256, 0, stream>>>(xBC, st, acs, ybuf);
        // 10. gated RMSNorm -> yn (bf16)
        gated_rms<<<Tg, 256, 0, stream>>>(ybuf, zx, norm_w, yn);
        // 11. out_proj (MFMA, BM=64 for block count): t2 = yn @ outW^T
        mfma_gemm<64, 0, false, false><<<dim3(DM / 128, Tg / 64, 1), 256, 0, stream>>>(
            yn, outW, nullptr, t2, DM, DI, DI, DI, DM, 0, 0, 0);
        // 12. t = LN(tgt + t2)
        add_ln<<<Tg, 256, 0, stream>>>(tgt_g, t2, norm1_w, norm1_b, tb, tbb);
        // 13. h1 = gelu(t @ w1^T + b1)
        mfma_gemm<128, 1, true, true><<<dim3(FF / 128, Tg / 128, 1), 256, 0, stream>>>(
            tbb, w1b, b1, h1, FF, DM, DM, DM, FF, 0, 0, 0);
        // 14. f = h1 @ w2^T + b2 (BM=64)
        mfma_gemm<64, 0, true, false><<<dim3(DM / 128, Tg / 64, 1), 256, 0, stream>>>(
            h1, w2b, b2, fb, DM, FF, FF, FF, DM, 0, 0, 0);
        // 15. out = LN(t + f)
        add_ln<<<Tg, 256, 0, stream>>>(tb, fb, norm3_w, norm3_b, out_g, dummy16);
    }
}

// Round 5
// 1001.541 us; speedup vs baseline: 2.4120x; 1.0759x over previous
//
#include <hip/hip_runtime.h>
#include <hip/hip_bf16.h>
#include <math.h>

// ---------------------------------------------------------------------------
// Mamba2 layer (round 4): SSD moved to MFMA.
//   ssd_states: st[p][n] = sum_j X^T[p][j] * (B[j][n] exp(el-acs_j) dt_j)
//   ssd_scan  : sequential inter-chunk recurrence (unchanged, elementwise)
//   ssd_out   : y[i][p] = sum_j W[i][j] X^T[p][j]            (phase 1, K=128)
//                       + sum_n (e^{acs_i} C[i][n]) prev[p][n](phase 2, K=128)
//                       + D_h * x[i][p]
//   Two MFMA phases share one A-buf + one B-buf => 52 KB LDS, 3 blocks/CU.
// GEMMs: register-staged LDS-double-buffered bf16 MFMA (round-3).
// ---------------------------------------------------------------------------

namespace {
constexpr int BB = 8;
constexpr int S = 2048;
constexpr int DM = 512;
constexpr int DIP = 2320;        // in_proj output dim
constexpr int DIPP = 2432;       // padded to 19*128 for MFMA tiles
constexpr int DI = 1024;         // d_inner
constexpr int CDIM = 1280;       // conv dim
constexpr int NH = 16;
constexpr int HD = 64;
constexpr int DSTATE = 128;
constexpr int CH = 128;          // chunk length
constexpr int NC = S / CH;       // 16 chunks
constexpr int FF = 2048;
constexpr float EPS = 1e-5f;
constexpr int LP = 132;          // padded K-row stride for SSD LDS tiles
}

using bf16_t = __hip_bfloat16;
typedef __attribute__((ext_vector_type(8))) short short8;   // 8 bf16 = 4 VGPR
typedef __attribute__((ext_vector_type(4))) float f32x4;

__device__ __forceinline__ float gelu_exact(float x) {
    return 0.5f * x * (1.0f + erff(x * 0.7071067811865476f));
}

__device__ __forceinline__ void block_sum2(float& a, float& b) {
    #pragma unroll
    for (int o = 32; o > 0; o >>= 1) {
        a += __shfl_down(a, o, 64);
        b += __shfl_down(b, o, 64);
    }
    __shared__ float sa[4], sb[4];
    int w = threadIdx.x >> 6;
    if ((threadIdx.x & 63) == 0) { sa[w] = a; sb[w] = b; }
    __syncthreads();
    a = sa[0] + sa[1] + sa[2] + sa[3];
    b = sb[0] + sb[1] + sb[2] + sb[3];
}

// ---------------------------------------------------------------------------
// bf16 MFMA GEMM, pipelined (round 3, unchanged).
// ---------------------------------------------------------------------------
template <int BM, int ACT, bool HASBIAS, bool OUTBF>
__global__ __launch_bounds__(256)
void mfma_gemm(const bf16_t* __restrict__ A, const bf16_t* __restrict__ W,
               const float* __restrict__ bias, void* __restrict__ Cout,
               int N, int K, int lda, int ldw, int ldc,
               long batchA, long batchW, long batchC)
{
    A += (long)blockIdx.z * batchA;
    W += (long)blockIdx.z * batchW;
    constexpr int ACH = BM / 64;
    constexpr int NJ = (BM == 128) ? 4 : 2;
    __shared__ bf16_t As[2][BM * 32];
    __shared__ bf16_t Ws[2][4096];
    const int tid = threadIdx.x;
    const int lane = tid & 63;
    const int wave = tid >> 6;
    const long bm = (long)blockIdx.y * BM;
    const int bn = blockIdx.x * 128;

    const int rA = tid & (BM - 1);
    const int qA = tid / BM;
    const int rW = tid & 127;
    const int qW = tid >> 7;
    const bf16_t* Ag = A + (bm + rA) * (long)lda + qA * 8;
    const bf16_t* Wg = W + ((long)bn + rW) * (long)ldw + qW * 8;
    const int laoff0 = (qA * BM + rA) * 8;
    const int laoff1 = ((qA + 2) * BM + rA) * 8;
    const int lwoff0 = (qW * 128 + rW) * 8;
    const int lwoff1 = ((qW + 2) * 128 + rW) * 8;

    const int kq = lane >> 4;
    const int lr = lane & 15;
    const int wm = (BM == 128) ? (wave & 1) * 64 : 0;
    const int wn = (BM == 128) ? (wave >> 1) * 64 : wave * 32;

    f32x4 acc[4][NJ];
    #pragma unroll
    for (int i = 0; i < 4; i++)
        #pragma unroll
        for (int j = 0; j < NJ; j++) acc[i][j] = (f32x4){0.f, 0.f, 0.f, 0.f};

    short8 ra0, ra1, rw0, rw1;
    ra0 = *(const short8*)Ag;
    if (ACH == 2) ra1 = *(const short8*)(Ag + 16);
    rw0 = *(const short8*)Wg;
    rw1 = *(const short8*)(Wg + 16);
    *(short8*)&As[0][laoff0] = ra0;
    if (ACH == 2) *(short8*)&As[0][laoff1] = ra1;
    *(short8*)&Ws[0][lwoff0] = rw0;
    *(short8*)&Ws[0][lwoff1] = rw1;

    const int nt = K / 32;
    for (int t = 0; t < nt; t++) {
        const int cur = t & 1, nxt = cur ^ 1;
        if (t + 1 < nt) {
            const int ko = (t + 1) * 32;
            ra0 = *(const short8*)(Ag + ko);
            if (ACH == 2) ra1 = *(const short8*)(Ag + ko + 16);
            rw0 = *(const short8*)(Wg + ko);
            rw1 = *(const short8*)(Wg + ko + 16);
        }
        __syncthreads();
        short8 af[4], bfr[NJ];
        #pragma unroll
        for (int i = 0; i < 4; i++)
            af[i] = *(const short8*)&As[cur][(kq * BM + wm + i * 16 + lr) * 8];
        #pragma unroll
        for (int j = 0; j < NJ; j++)
            bfr[j] = *(const short8*)&Ws[cur][(kq * 128 + wn + j * 16 + lr) * 8];
        #pragma unroll
        for (int i = 0; i < 4; i++)
            #pragma unroll
            for (int j = 0; j < NJ; j++)
                acc[i][j] = __builtin_amdgcn_mfma_f32_16x16x32_bf16(af[i], bfr[j], acc[i][j], 0, 0, 0);
        if (t + 1 < nt) {
            *(short8*)&As[nxt][laoff0] = ra0;
            if (ACH == 2) *(short8*)&As[nxt][laoff1] = ra1;
            *(short8*)&Ws[nxt][lwoff0] = rw0;
            *(short8*)&Ws[nxt][lwoff1] = rw1;
        }
    }

    #pragma unroll
    for (int i = 0; i < 4; i++) {
        #pragma unroll
        for (int j = 0; j < NJ; j++) {
            int col = bn + wn + j * 16 + lr;
            if (col < N) {
                float bv = HASBIAS ? bias[col] : 0.f;
                #pragma unroll
                for (int r = 0; r < 4; r++) {
                    long row = bm + wm + i * 16 + kq * 4 + r;
                    float v = acc[i][j][r] + bv;
                    if (ACT == 1) v = gelu_exact(v);
                    if (OUTBF) ((bf16_t*)Cout)[row * (long)ldc + col + blockIdx.z * batchC] = __float2bfloat16(v);
                    else       ((float*)Cout)[row * (long)ldc + col + blockIdx.z * batchC] = v;
                }
            }
        }
    }
}

// ---------------------------------------------------------------------------
// f32 GEMM for the tiny dt projection (N=16).
// ---------------------------------------------------------------------------
template <int ACT, bool HASBIAS>
__global__ __launch_bounds__(256)
void gemm_kernel(const float* __restrict__ A, const float* __restrict__ W,
                 const float* __restrict__ bias, float* __restrict__ C,
                 int M, int N, int K, int lda, int ldw, int ldc,
                 long batchA, long batchW, long batchC)
{
    A += (long)blockIdx.z * batchA;
    W += (long)blockIdx.z * batchW;
    C += (long)blockIdx.z * batchC;
    __shared__ __align__(16) float Asm[16][68];
    __shared__ __align__(16) float Wsm[16][68];
    const int tid = threadIdx.x;
    const int bm = blockIdx.y * 64;
    const int bn = blockIdx.x * 64;
    const int tm = (tid & 15) * 4;
    const int tn = (tid >> 4) * 4;
    const int lr = tid >> 2;
    const int lk = (tid & 3) * 4;
    const float* Ap = A + (long)(bm + lr) * lda + lk;
    const float* Wp = W + (long)(bn + lr) * ldw + lk;
    const bool wv_ok = (bn + lr) < N;
    float acc[4][4];
    #pragma unroll
    for (int i = 0; i < 4; i++)
        #pragma unroll
        for (int j = 0; j < 4; j++) acc[i][j] = 0.f;

    for (int k0 = 0; k0 < K; k0 += 16) {
        float4 av = *(const float4*)(Ap + k0);
        float4 wv = wv_ok ? *(const float4*)(Wp + k0) : make_float4(0.f, 0.f, 0.f, 0.f);
        Asm[lk + 0][lr] = av.x; Asm[lk + 1][lr] = av.y;
        Asm[lk + 2][lr] = av.z; Asm[lk + 3][lr] = av.w;
        Wsm[lk + 0][lr] = wv.x; Wsm[lk + 1][lr] = wv.y;
        Wsm[lk + 2][lr] = wv.z; Wsm[lk + 3][lr] = wv.w;
        __syncthreads();
        #pragma unroll
        for (int k = 0; k < 16; k++) {
            float4 a = *(const float4*)&Asm[k][tm];
            float4 w = *(const float4*)&Wsm[k][tn];
            acc[0][0] += a.x * w.x; acc[0][1] += a.x * w.y; acc[0][2] += a.x * w.z; acc[0][3] += a.x * w.w;
            acc[1][0] += a.y * w.x; acc[1][1] += a.y * w.y; acc[1][2] += a.y * w.z; acc[1][3] += a.y * w.w;
            acc[2][0] += a.z * w.x; acc[2][1] += a.z * w.y; acc[2][2] += a.z * w.z; acc[2][3] += a.z * w.w;
            acc[3][0] += a.w * w.x; acc[3][1] += a.w * w.y; acc[3][2] += a.w * w.z; acc[3][3] += a.w * w.w;
        }
        __syncthreads();
    }
    #pragma unroll
    for (int i = 0; i < 4; i++) {
        long row = bm + tm + i;
        #pragma unroll
        for (int j = 0; j < 4; j++) {
            int col = bn + tn + j;
            if (col < N) {
                float v = acc[i][j];
                if (HASBIAS) v += bias[col];
                if (ACT == 1) v = gelu_exact(v);
                C[row * ldc + col] = v;
            }
        }
    }
}

// ---------------------------------------------------------------------------
__global__ __launch_bounds__(256)
void cvt_bf16(const float* __restrict__ s, bf16_t* __restrict__ d, long n)
{
    long i = ((long)blockIdx.x * 256 + threadIdx.x) * 4;
    if (i >= n) return;
    float4 v = *(const float4*)(s + i);
    d[i + 0] = __float2bfloat16(v.x);
    d[i + 1] = __float2bfloat16(v.y);
    d[i + 2] = __float2bfloat16(v.z);
    d[i + 3] = __float2bfloat16(v.w);
}

__global__ __launch_bounds__(256)
void cvt_bf16_pad(const float* __restrict__ s, bf16_t* __restrict__ d,
                  int rows_src, long total, int cols)
{
    long i = (long)blockIdx.x * 256 + threadIdx.x;
    if (i >= total) return;
    long r = i / cols;
    d[i] = __float2bfloat16(r < rows_src ? s[i] : 0.f);
}

// ---------------------------------------------------------------------------
__global__ __launch_bounds__(256)
void conv_silu_kernel(const bf16_t* __restrict__ zx, const float* __restrict__ cw,
                      const float* __restrict__ cb, bf16_t* __restrict__ xBC, long count)
{
    long idx = (long)blockIdx.x * 256 + threadIdx.x;
    if (idx >= count) return;
    int c = (int)(idx % CDIM);
    long t = idx / CDIM;
    int s = (int)(t % S);
    float v = cb[c];
    #pragma unroll
    for (int k = 0; k < 4; k++) {
        int sp = s + k - 3;
        if (sp >= 0) v += __bfloat162float(zx[(t + k - 3) * DIP + DI + c]) * cw[c * 4 + k];
    }
    v = v / (1.f + __expf(-v));
    xBC[idx] = __float2bfloat16(v);
}

__global__ __launch_bounds__(256)
void dt_kernel(const float* __restrict__ raw, const float* __restrict__ dt_bias,
               float* __restrict__ dts, long count)
{
    long idx = (long)blockIdx.x * 256 + threadIdx.x;
    if (idx >= count) return;
    float x = raw[idx] + dt_bias[idx & 15];
    dts[idx] = (x > 20.f) ? x : log1pf(__expf(x));
}

// ---------------------------------------------------------------------------
// SSD states (MFMA): per (b,c,h) block computes
//   st[p][n] = sum_j X^T[p][j] * Bw^T[n][j],  Bw[j][n] = B[j][n]*exp(el-acs_j)*dt_j
// Also stores acs_all and cdlog. LDS ~52 KB.
// ---------------------------------------------------------------------------
__global__ __launch_bounds__(256)
void ssd_states(const bf16_t* __restrict__ xBC, const float* __restrict__ dts,
                const float* __restrict__ A_log,
                float* __restrict__ st, float* __restrict__ acs_all,
                float* __restrict__ cdlog)
{
    const int bid = blockIdx.x;
    const int h = bid & 15;
    const int c = (bid >> 4) & 15;
    const int b = bid >> 8;
    const int tid = threadIdx.x;
    const int lane = tid & 63;
    const int wave = tid >> 6;
    __shared__ float dtv[128];
    __shared__ float acs[128];
    __shared__ float wj[128];
    __shared__ bf16_t XT[64 * LP];      // X^T[p][j]
    __shared__ bf16_t BwT[128 * LP];    // Bw^T[n][j]
    const long t0 = (long)b * S + (long)c * CH;
    const float Ah = -__expf(A_log[h]);

    if (tid < 128) {
        float d = dts[(t0 + tid) * NH + h];
        dtv[tid] = d;
        acs[tid] = d * Ah;
    }
    __syncthreads();
    for (int off = 1; off < 128; off <<= 1) {
        float add = 0.f;
        if (tid < 128 && tid >= off) add = acs[tid - off];
        __syncthreads();
        if (tid < 128 && tid >= off) acs[tid] += add;
        __syncthreads();
    }
    const float el = acs[127];
    if (tid < 128) {
        acs_all[(long)bid * 128 + tid] = acs[tid];
        wj[tid] = __expf(el - acs[tid]) * dtv[tid];
    }
    if (tid == 0) cdlog[bid] = el;
    __syncthreads();

    // stage X^T (transpose) and Bw^T (transpose, scaled)
    for (int i = tid; i < 128 * 64; i += 256) {
        int j = i >> 6, p = i & 63;
        XT[p * LP + j] = xBC[(t0 + j) * CDIM + h * HD + p];
    }
    for (int i = tid; i < 128 * 128; i += 256) {
        int j = i >> 7, n = i & 127;
        float v = __bfloat162float(xBC[(t0 + j) * CDIM + DI + n]) * wj[j];
        BwT[n * LP + j] = __float2bfloat16(v);
    }
    __syncthreads();

    // MFMA: D[p][n], 64x128, K=128. Wave handles n in [wave*32, wave*32+32).
    const int kq = lane >> 4;
    const int lr = lane & 15;
    const int n0 = wave * 32;
    f32x4 acc[4][2];
    #pragma unroll
    for (int i = 0; i < 4; i++)
        #pragma unroll
        for (int j = 0; j < 2; j++) acc[i][j] = (f32x4){0.f, 0.f, 0.f, 0.f};
    #pragma unroll
    for (int t = 0; t < 4; t++) {
        short8 af[4], bfr[2];
        #pragma unroll
        for (int i = 0; i < 4; i++)
            af[i] = *(const short8*)&XT[(i * 16 + lr) * LP + t * 32 + kq * 8];
        #pragma unroll
        for (int j = 0; j < 2; j++)
            bfr[j] = *(const short8*)&BwT[(n0 + j * 16 + lr) * LP + t * 32 + kq * 8];
        #pragma unroll
        for (int i = 0; i < 4; i++)
            #pragma unroll
            for (int j = 0; j < 2; j++)
                acc[i][j] = __builtin_amdgcn_mfma_f32_16x16x32_bf16(af[i], bfr[j], acc[i][j], 0, 0, 0);
    }
    long base = (long)bid * 8192;
    #pragma unroll
    for (int i = 0; i < 4; i++)
        #pragma unroll
        for (int j = 0; j < 2; j++) {
            int col = n0 + j * 16 + lr;
            #pragma unroll
            for (int r = 0; r < 4; r++) {
                int row = i * 16 + kq * 4 + r;   // p
                st[base + row * 128 + col] = acc[i][j][r];
            }
        }
}

// ---------------------------------------------------------------------------
// Inter-chunk sequential scan; in-place (elementwise, layout-agnostic).
// ---------------------------------------------------------------------------
__global__ __launch_bounds__(256)
void ssd_scan(float* __restrict__ st, const float* __restrict__ cdlog)
{
    const int h = blockIdx.x & 15;
    const int b = blockIdx.x >> 4;
    const int tid = threadIdx.x;
    float prev[32];
    #pragma unroll
    for (int q = 0; q < 32; q++) prev[q] = 0.f;
    for (int c = 0; c < NC; c++) {
        int bc = (b * NC + c) * NH + h;
        float cd = __expf(cdlog[bc]);
        long base = (long)bc * 8192;
        #pragma unroll
        for (int q = 0; q < 32; q++) {
            long idx = base + (long)q * 256 + tid;
            float v = st[idx];
            st[idx] = prev[q];
            prev[q] = cd * prev[q] + v;
        }
    }
}

// ---------------------------------------------------------------------------
// SSD output (MFMA, fused diag+off+D*x): per (b,c,h) block:
//   phase 1: A=W[i][j] (masked decay * G), B=X^T[p][j]      -> acc
//            + read X for the D*x term from B-buf before overwrite
//   phase 2: A=e^{acs_i} C[i][n], B=prev[p][n]              -> acc
//   y[i][p] = acc + D_h * x[i][p]
// One shared A-buf (128xLP) + one B-buf (64xLP); LDS ~52 KB.
// ---------------------------------------------------------------------------
__global__ __launch_bounds__(256)
void ssd_out(const bf16_t* __restrict__ xBC, const float* __restrict__ dts,
             const float* __restrict__ G, const float* __restrict__ st,
             const float* __restrict__ acs_all, const float* __restrict__ D_head,
             float* __restrict__ y)
{
    const int bid = blockIdx.x;
    const int h = bid & 15;
    const int c = (bid >> 4) & 15;
    const int b = bid >> 8;
    const int tid = threadIdx.x;
    const int lane = tid & 63;
    const int wave = tid >> 6;
    __shared__ float dtv[128];
    __shared__ float acs[128];
    __shared__ float eacs[128];
    __shared__ bf16_t Abuf[128 * LP];
    __shared__ bf16_t Bbuf[64 * LP];
    const long t0 = (long)b * S + (long)c * CH;

    if (tid < 128) {
        dtv[tid] = dts[(t0 + tid) * NH + h];
        float a = acs_all[(long)bid * 128 + tid];
        acs[tid] = a;
        eacs[tid] = __expf(a);
    }
    __syncthreads();

    // phase-1 staging: W and X^T
    const float* Gb = G + (long)(b * NC + c) * 128 * 128;
    for (int i = tid; i < 128 * 128; i += 256) {
        int row = i >> 7, k = i & 127;
        float v = (k <= row) ? Gb[i] * __expf(acs[row] - acs[k]) * dtv[k] : 0.f;
        Abuf[row * LP + k] = __float2bfloat16(v);
    }
    for (int i = tid; i < 128 * 64; i += 256) {
        int j = i >> 6, p = i & 63;
        Bbuf[p * LP + j] = xBC[(t0 + j) * CDIM + h * HD + p];
    }
    __syncthreads();

    const int kq = lane >> 4;
    const int lr = lane & 15;
    const int m0 = (wave & 1) * 64;
    const int p0 = (wave >> 1) * 32;
    f32x4 acc[4][2];
    #pragma unroll
    for (int i = 0; i < 4; i++)
        #pragma unroll
        for (int j = 0; j < 2; j++) acc[i][j] = (f32x4){0.f, 0.f, 0.f, 0.f};

    #pragma unroll
    for (int t = 0; t < 4; t++) {
        short8 af[4], bfr[2];
        #pragma unroll
        for (int i = 0; i < 4; i++)
            af[i] = *(const short8*)&Abuf[(m0 + i * 16 + lr) * LP + t * 32 + kq * 8];
        #pragma unroll
        for (int j = 0; j < 2; j++)
            bfr[j] = *(const short8*)&Bbuf[(p0 + j * 16 + lr) * LP + t * 32 + kq * 8];
        #pragma unroll
        for (int i = 0; i < 4; i++)
            #pragma unroll
            for (int j = 0; j < 2; j++)
                acc[i][j] = __builtin_amdgcn_mfma_f32_16x16x32_bf16(af[i], bfr[j], acc[i][j], 0, 0, 0);
    }
    // D*x term: read x[i][p] from Bbuf (X^T) before it is overwritten
    const float Dh = D_head[h];
    float dx[4][2][4];
    #pragma unroll
    for (int i = 0; i < 4; i++)
        #pragma unroll
        for (int j = 0; j < 2; j++) {
            int col = p0 + j * 16 + lr;
            #pragma unroll
            for (int r = 0; r < 4; r++) {
                int row = m0 + i * 16 + kq * 4 + r;
                dx[i][j][r] = Dh * __bfloat162float(Bbuf[col * LP + row]);
            }
        }
    __syncthreads();

    // phase-2 staging: e^{acs_i} * C and prev
    for (int i = tid; i < 128 * 128; i += 256) {
        int row = i >> 7, n = i & 127;
        float v = eacs[row] * __bfloat162float(xBC[(t0 + row) * CDIM + DI + DSTATE + n]);
        Abuf[row * LP + n] = __float2bfloat16(v);
    }
    for (int i = tid; i < 64 * 128; i += 256) {
        int p = i >> 7, n = i & 127;
        Bbuf[p * LP + n] = __float2bfloat16(st[(long)bid * 8192 + i]);
    }
    __syncthreads();

    #pragma unroll
    for (int t = 0; t < 4; t++) {
        short8 af[4], bfr[2];
        #pragma unroll
        for (int i = 0; i < 4; i++)
            af[i] = *(const short8*)&Abuf[(m0 + i * 16 + lr) * LP + t * 32 + kq * 8];
        #pragma unroll
        for (int j = 0; j < 2; j++)
            bfr[j] = *(const short8*)&Bbuf[(p0 + j * 16 + lr) * LP + t * 32 + kq * 8];
        #pragma unroll
        for (int i = 0; i < 4; i++)
            #pragma unroll
            for (int j = 0; j < 2; j++)
                acc[i][j] = __builtin_amdgcn_mfma_f32_16x16x32_bf16(af[i], bfr[j], acc[i][j], 0, 0, 0);
    }

    #pragma unroll
    for (int i = 0; i < 4; i++)
        #pragma unroll
        for (int j = 0; j < 2; j++) {
            int col = p0 + j * 16 + lr;    // p
            #pragma unroll
            for (int r = 0; r < 4; r++) {
                int row = m0 + i * 16 + kq * 4 + r;   // time i
                y[(t0 + row) * DI + h * HD + col] = acc[i][j][r] + dx[i][j][r];
            }
        }
}

// ---------------------------------------------------------------------------
__global__ __launch_bounds__(256)
void gated_rms(const float* __restrict__ y, const bf16_t* __restrict__ zx,
               const float* __restrict__ norm_w, bf16_t* __restrict__ yn)
{
    const long t = blockIdx.x;
    const int tid = threadIdx.x;
    float g[4];
    float ss = 0.f, dummy = 0.f;
    #pragma unroll
    for (int q = 0; q < 4; q++) {
        int d = tid + q * 256;
        float zv = __bfloat162float(zx[t * DIP + d]);
        float yv = y[t * DI + d];
        float gv = yv * (zv / (1.f + __expf(-zv)));
        g[q] = gv;
        ss += gv * gv;
    }
    block_sum2(ss, dummy);
    float scale = rsqrtf(ss * (1.f / DI) + EPS);
    #pragma unroll
    for (int q = 0; q < 4; q++) {
        int d = tid + q * 256;
        yn[t * DI + d] = __float2bfloat16(g[q] * scale * norm_w[d]);
    }
}

// ---------------------------------------------------------------------------
__global__ __launch_bounds__(256)
void add_ln(const float* __restrict__ x, const float* __restrict__ r,
            const float* __restrict__ w, const float* __restrict__ bpar,
            float* __restrict__ o32, bf16_t* __restrict__ o16)
{
    const long t = blockIdx.x;
    const int tid = threadIdx.x;
    float v[2];
    float s = 0.f, s2 = 0.f;
    #pragma unroll
    for (int q = 0; q < 2; q++) {
        int d = tid + q * 256;
        float vv = x[t * DM + d] + r[t * DM + d];
        v[q] = vv;
        s += vv;
        s2 += vv * vv;
    }
    block_sum2(s, s2);
    float mean = s * (1.f / DM);
    float var = s2 * (1.f / DM) - mean * mean;
    float inv = rsqrtf(var + EPS);
    #pragma unroll
    for (int q = 0; q < 2; q++) {
        int d = tid + q * 256;
        float o = (v[q] - mean) * inv * w[d] + bpar[d];
        o32[t * DM + d] = o;
        o16[t * DM + d] = __float2bfloat16(o);
    }
}

// ---------------------------------------------------------------------------

extern "C" void kernel_launch(void* const* d_in, const int* in_sizes, int n_in,
                              void* d_out, int out_size, void* d_ws, size_t ws_size,
                              hipStream_t stream)
{
    const float* tgt       = (const float*)d_in[0];
    const float* in_proj_w = (const float*)d_in[5];
    const float* conv_w    = (const float*)d_in[6];
    const float* conv_b    = (const float*)d_in[7];
    const float* dt_bias   = (const float*)d_in[8];
    const float* A_log     = (const float*)d_in[9];
    const float* D_head    = (const float*)d_in[10];
    const float* norm_w    = (const float*)d_in[11];
    const float* out_proj_w= (const float*)d_in[12];
    const float* norm1_w   = (const float*)d_in[13];
    const float* norm1_b   = (const float*)d_in[14];
    const float* w1        = (const float*)d_in[15];
    const float* b1        = (const float*)d_in[16];
    const float* w2        = (const float*)d_in[17];
    const float* b2        = (const float*)d_in[18];
    const float* norm3_w   = (const float*)d_in[19];
    const float* norm3_b   = (const float*)d_in[20];
    float* out = (float*)d_out;

    float* ws = (float*)d_ws;

    const size_t SZ_INW  = (size_t)DIPP * DM / 2;
    const size_t SZ_OUTW = (size_t)DM * DI / 2;
    const size_t SZ_W1   = (size_t)FF * DM / 2;
    const size_t SZ_W2   = (size_t)DM * FF / 2;
    size_t wo = 0;
    bf16_t* inW  = (bf16_t*)(ws + wo); wo += SZ_INW;
    bf16_t* outW = (bf16_t*)(ws + wo); wo += SZ_OUTW;
    bf16_t* w1b  = (bf16_t*)(ws + wo); wo += SZ_W1;
    bf16_t* w2b  = (bf16_t*)(ws + wo); wo += SZ_W2;
    const size_t WB = wo;

    const size_t PB = (size_t)S * DM / 2            // tgt_bf
                    + (size_t)S * DIP / 2           // zx_bf
                    + (size_t)S * NH                // dts_raw
                    + (size_t)S * NH                // dts
                    + (size_t)S * CDIM / 2          // xBC_bf
                    + (size_t)NC * 128 * 128        // G
                    + (size_t)NC * NH * 128         // acs
                    + (size_t)NC * NH               // cdl
                    + (size_t)S * DI                // y
                    + (size_t)S * DI;               // st
    int NB = 0;
    for (int nb = 8; nb >= 1; nb >>= 1) {
        if (ws_size >= (WB + (size_t)nb * PB) * sizeof(float)) { NB = nb; break; }
    }
    if (NB == 0) return;

    {
        long n = (long)DIPP * DM;
        cvt_bf16_pad<<<(n + 255) / 256, 256, 0, stream>>>(in_proj_w, inW, DIP, n, DM);
        n = (long)DM * DI;
        cvt_bf16<<<(n / 4 + 255) / 256, 256, 0, stream>>>(out_proj_w, outW, n);
        n = (long)FF * DM;
        cvt_bf16<<<(n / 4 + 255) / 256, 256, 0, stream>>>(w1, w1b, n);
        n = (long)DM * FF;
        cvt_bf16<<<(n / 4 + 255) / 256, 256, 0, stream>>>(w2, w2b, n);
    }

    for (int b0 = 0; b0 < BB; b0 += NB) {
        const long Tg = (long)NB * S;
        size_t o = WB;
        bf16_t* tgt_bf = (bf16_t*)(ws + o); o += (size_t)Tg * DM / 2;
        bf16_t* zx     = (bf16_t*)(ws + o); o += (size_t)Tg * DIP / 2;
        float*  dts_raw= ws + o;            o += (size_t)Tg * NH;
        float*  dts    = ws + o;            o += (size_t)Tg * NH;
        bf16_t* xBC    = (bf16_t*)(ws + o); o += (size_t)Tg * CDIM / 2;
        float*  G      = ws + o;            o += (size_t)NB * NC * 128 * 128;
        float*  acs    = ws + o;            o += (size_t)NB * NC * NH * 128;
        float*  cdl    = ws + o;            o += (size_t)NB * NC * NH;
        float*  ybuf   = ws + o;            o += (size_t)Tg * DI;
        float*  st     = ws + o;            o += (size_t)Tg * DI;

        bf16_t* yn  = (bf16_t*)st;                       // after ssd_out
        float*  t2  = ybuf;                              // after gated_rms
        float*  tb  = (float*)zx;                        // t f32
        bf16_t* tbb = (bf16_t*)(((float*)zx) + Tg * DM); // t bf16
        bf16_t* h1  = (bf16_t*)ybuf;                     // after add_ln1
        float*  fb  = (float*)xBC;                       // after ssd_out
        bf16_t* dummy16 = tbb;

        const float* tgt_g = tgt + (long)b0 * S * DM;
        float* out_g = out + (long)b0 * S * DM;

        cvt_bf16<<<((Tg * DM) / 4 + 255) / 256, 256, 0, stream>>>(tgt_g, tgt_bf, Tg * DM);
        mfma_gemm<128, 0, false, true><<<dim3(DIPP / 128, Tg / 128, 1), 256, 0, stream>>>(
            tgt_bf, inW, nullptr, zx, DIP, DM, DM, DM, DIP, 0, 0, 0);
        gemm_kernel<0, false><<<dim3(1, Tg / 64, 1), 256, 0, stream>>>(
            tgt_g, in_proj_w + (long)(DI + CDIM) * DM, nullptr, dts_raw,
            Tg, NH, DM, DM, DM, NH, 0, 0, 0);
        dt_kernel<<<(Tg * NH) / 256, 256, 0, stream>>>(dts_raw, dt_bias, dts, Tg * NH);
        conv_silu_kernel<<<(Tg * CDIM) / 256, 256, 0, stream>>>(zx, conv_w, conv_b, xBC, Tg * CDIM);
        // G = C @ B^T per chunk
        mfma_gemm<128, 0, false, false><<<dim3(1, 1, NB * NC), 256, 0, stream>>>(
            xBC + DI + DSTATE, xBC + DI, nullptr, G,
            128, DSTATE, CDIM, CDIM, 128,
            (long)CH * CDIM, (long)CH * CDIM, (long)128 * 128);
        // SSD (MFMA)
        ssd_states<<<NB * NC * NH, 256, 0, stream>>>(xBC, dts, A_log, st, acs, cdl);
        ssd_scan<<<NB * NH, 256, 0, stream>>>(st, cdl);
        ssd_out<<<NB * NC * NH, 256, 0, stream>>>(xBC, dts, G, st, acs, D_head, ybuf);
        gated_rms<<<Tg, 256, 0, stream>>>(ybuf, zx, norm_w, yn);
        mfma_gemm<64, 0, false, false><<<dim3(DM / 128, Tg / 64, 1), 256, 0, stream>>>(
            yn, outW, nullptr, t2, DM, DI, DI, DI, DM, 0, 0, 0);
        add_ln<<<Tg, 256, 0, stream>>>(tgt_g, t2, norm1_w, norm1_b, tb, tbb);
        mfma_gemm<128, 1, true, true><<<dim3(FF / 128, Tg / 128, 1), 256, 0, stream>>>(
            tbb, w1b, b1, h1, FF, DM, DM, DM, FF, 0, 0, 0);
        mfma_gemm<64, 0, true, false><<<dim3(DM / 128, Tg / 64, 1), 256, 0, stream>>>(
            h1, w2b, b2, fb, DM, FF, FF, FF, DM, 0, 0, 0);
        add_ln<<<Tg, 256, 0, stream>>>(tb, fb, norm3_w, norm3_b, out_g, dummy16);
    }
}

// Round 6
// 963.242 us; speedup vs baseline: 2.5079x; 1.0398x over previous
//
#include <hip/hip_runtime.h>
#include <hip/hip_bf16.h>
#include <math.h>

// ---------------------------------------------------------------------------
// Mamba2 layer (round 5):
//  - G stored bf16 (halves ssd_out's dominant fetch stream)
//  - ssd_states / ssd_out split per half (n-cols / i-rows): LDS 52->35 KB
//    (4 blocks/CU), grid x2, all LDS staging packed as 4-byte writes
//  - ssd_scan parallelized over q-slices (grid x4)
//  - y kept in bf16 (ssd_out write + gated_rms read halved)
//  - conv+silu vectorized 4 channels/thread
// ---------------------------------------------------------------------------

namespace {
constexpr int BB = 8;
constexpr int S = 2048;
constexpr int DM = 512;
constexpr int DIP = 2320;
constexpr int DIPP = 2432;       // padded to 19*128
constexpr int DI = 1024;
constexpr int CDIM = 1280;
constexpr int NH = 16;
constexpr int HD = 64;
constexpr int DSTATE = 128;
constexpr int CH = 128;
constexpr int NC = S / CH;       // 16
constexpr int FF = 2048;
constexpr float EPS = 1e-5f;
constexpr int LP = 132;          // padded K stride for SSD LDS tiles
}

using bf16_t = __hip_bfloat16;
typedef __attribute__((ext_vector_type(8))) short short8;
typedef __attribute__((ext_vector_type(4))) float f32x4;

__device__ __forceinline__ float gelu_exact(float x) {
    return 0.5f * x * (1.0f + erff(x * 0.7071067811865476f));
}
__device__ __forceinline__ unsigned short f2bfu(float f) {
    bf16_t b = __float2bfloat16(f);
    return *(unsigned short*)&b;
}
__device__ __forceinline__ float bfu2f(unsigned short u) {
    union { unsigned int i; float f; } v; v.i = (unsigned)u << 16; return v.f;
}

__device__ __forceinline__ void block_sum2(float& a, float& b) {
    #pragma unroll
    for (int o = 32; o > 0; o >>= 1) {
        a += __shfl_down(a, o, 64);
        b += __shfl_down(b, o, 64);
    }
    __shared__ float sa[4], sb[4];
    int w = threadIdx.x >> 6;
    if ((threadIdx.x & 63) == 0) { sa[w] = a; sb[w] = b; }
    __syncthreads();
    a = sa[0] + sa[1] + sa[2] + sa[3];
    b = sb[0] + sb[1] + sb[2] + sb[3];
}

// ---------------------------------------------------------------------------
// bf16 MFMA GEMM, register-staged + LDS double-buffered (round 3).
// ---------------------------------------------------------------------------
template <int BM, int ACT, bool HASBIAS, bool OUTBF>
__global__ __launch_bounds__(256)
void mfma_gemm(const bf16_t* __restrict__ A, const bf16_t* __restrict__ W,
               const float* __restrict__ bias, void* __restrict__ Cout,
               int N, int K, int lda, int ldw, int ldc,
               long batchA, long batchW, long batchC)
{
    A += (long)blockIdx.z * batchA;
    W += (long)blockIdx.z * batchW;
    constexpr int ACH = BM / 64;
    constexpr int NJ = (BM == 128) ? 4 : 2;
    __shared__ bf16_t As[2][BM * 32];
    __shared__ bf16_t Ws[2][4096];
    const int tid = threadIdx.x;
    const int lane = tid & 63;
    const int wave = tid >> 6;
    const long bm = (long)blockIdx.y * BM;
    const int bn = blockIdx.x * 128;

    const int rA = tid & (BM - 1);
    const int qA = tid / BM;
    const int rW = tid & 127;
    const int qW = tid >> 7;
    const bf16_t* Ag = A + (bm + rA) * (long)lda + qA * 8;
    const bf16_t* Wg = W + ((long)bn + rW) * (long)ldw + qW * 8;
    const int laoff0 = (qA * BM + rA) * 8;
    const int laoff1 = ((qA + 2) * BM + rA) * 8;
    const int lwoff0 = (qW * 128 + rW) * 8;
    const int lwoff1 = ((qW + 2) * 128 + rW) * 8;

    const int kq = lane >> 4;
    const int lr = lane & 15;
    const int wm = (BM == 128) ? (wave & 1) * 64 : 0;
    const int wn = (BM == 128) ? (wave >> 1) * 64 : wave * 32;

    f32x4 acc[4][NJ];
    #pragma unroll
    for (int i = 0; i < 4; i++)
        #pragma unroll
        for (int j = 0; j < NJ; j++) acc[i][j] = (f32x4){0.f, 0.f, 0.f, 0.f};

    short8 ra0, ra1, rw0, rw1;
    ra0 = *(const short8*)Ag;
    if (ACH == 2) ra1 = *(const short8*)(Ag + 16);
    rw0 = *(const short8*)Wg;
    rw1 = *(const short8*)(Wg + 16);
    *(short8*)&As[0][laoff0] = ra0;
    if (ACH == 2) *(short8*)&As[0][laoff1] = ra1;
    *(short8*)&Ws[0][lwoff0] = rw0;
    *(short8*)&Ws[0][lwoff1] = rw1;

    const int nt = K / 32;
    for (int t = 0; t < nt; t++) {
        const int cur = t & 1, nxt = cur ^ 1;
        if (t + 1 < nt) {
            const int ko = (t + 1) * 32;
            ra0 = *(const short8*)(Ag + ko);
            if (ACH == 2) ra1 = *(const short8*)(Ag + ko + 16);
            rw0 = *(const short8*)(Wg + ko);
            rw1 = *(const short8*)(Wg + ko + 16);
        }
        __syncthreads();
        short8 af[4], bfr[NJ];
        #pragma unroll
        for (int i = 0; i < 4; i++)
            af[i] = *(const short8*)&As[cur][(kq * BM + wm + i * 16 + lr) * 8];
        #pragma unroll
        for (int j = 0; j < NJ; j++)
            bfr[j] = *(const short8*)&Ws[cur][(kq * 128 + wn + j * 16 + lr) * 8];
        #pragma unroll
        for (int i = 0; i < 4; i++)
            #pragma unroll
            for (int j = 0; j < NJ; j++)
                acc[i][j] = __builtin_amdgcn_mfma_f32_16x16x32_bf16(af[i], bfr[j], acc[i][j], 0, 0, 0);
        if (t + 1 < nt) {
            *(short8*)&As[nxt][laoff0] = ra0;
            if (ACH == 2) *(short8*)&As[nxt][laoff1] = ra1;
            *(short8*)&Ws[nxt][lwoff0] = rw0;
            *(short8*)&Ws[nxt][lwoff1] = rw1;
        }
    }

    #pragma unroll
    for (int i = 0; i < 4; i++) {
        #pragma unroll
        for (int j = 0; j < NJ; j++) {
            int col = bn + wn + j * 16 + lr;
            if (col < N) {
                float bv = HASBIAS ? bias[col] : 0.f;
                #pragma unroll
                for (int r = 0; r < 4; r++) {
                    long row = bm + wm + i * 16 + kq * 4 + r;
                    float v = acc[i][j][r] + bv;
                    if (ACT == 1) v = gelu_exact(v);
                    if (OUTBF) ((bf16_t*)Cout)[row * (long)ldc + col + blockIdx.z * batchC] = __float2bfloat16(v);
                    else       ((float*)Cout)[row * (long)ldc + col + blockIdx.z * batchC] = v;
                }
            }
        }
    }
}

// ---------------------------------------------------------------------------
// f32 GEMM for the tiny dt projection (N=16).
// ---------------------------------------------------------------------------
template <int ACT, bool HASBIAS>
__global__ __launch_bounds__(256)
void gemm_kernel(const float* __restrict__ A, const float* __restrict__ W,
                 const float* __restrict__ bias, float* __restrict__ C,
                 int M, int N, int K, int lda, int ldw, int ldc,
                 long batchA, long batchW, long batchC)
{
    A += (long)blockIdx.z * batchA;
    W += (long)blockIdx.z * batchW;
    C += (long)blockIdx.z * batchC;
    __shared__ __align__(16) float Asm[16][68];
    __shared__ __align__(16) float Wsm[16][68];
    const int tid = threadIdx.x;
    const int bm = blockIdx.y * 64;
    const int bn = blockIdx.x * 64;
    const int tm = (tid & 15) * 4;
    const int tn = (tid >> 4) * 4;
    const int lr = tid >> 2;
    const int lk = (tid & 3) * 4;
    const float* Ap = A + (long)(bm + lr) * lda + lk;
    const float* Wp = W + (long)(bn + lr) * ldw + lk;
    const bool wv_ok = (bn + lr) < N;
    float acc[4][4];
    #pragma unroll
    for (int i = 0; i < 4; i++)
        #pragma unroll
        for (int j = 0; j < 4; j++) acc[i][j] = 0.f;

    for (int k0 = 0; k0 < K; k0 += 16) {
        float4 av = *(const float4*)(Ap + k0);
        float4 wv = wv_ok ? *(const float4*)(Wp + k0) : make_float4(0.f, 0.f, 0.f, 0.f);
        Asm[lk + 0][lr] = av.x; Asm[lk + 1][lr] = av.y;
        Asm[lk + 2][lr] = av.z; Asm[lk + 3][lr] = av.w;
        Wsm[lk + 0][lr] = wv.x; Wsm[lk + 1][lr] = wv.y;
        Wsm[lk + 2][lr] = wv.z; Wsm[lk + 3][lr] = wv.w;
        __syncthreads();
        #pragma unroll
        for (int k = 0; k < 16; k++) {
            float4 a = *(const float4*)&Asm[k][tm];
            float4 w = *(const float4*)&Wsm[k][tn];
            acc[0][0] += a.x * w.x; acc[0][1] += a.x * w.y; acc[0][2] += a.x * w.z; acc[0][3] += a.x * w.w;
            acc[1][0] += a.y * w.x; acc[1][1] += a.y * w.y; acc[1][2] += a.y * w.z; acc[1][3] += a.y * w.w;
            acc[2][0] += a.z * w.x; acc[2][1] += a.z * w.y; acc[2][2] += a.z * w.z; acc[2][3] += a.z * w.w;
            acc[3][0] += a.w * w.x; acc[3][1] += a.w * w.y; acc[3][2] += a.w * w.z; acc[3][3] += a.w * w.w;
        }
        __syncthreads();
    }
    #pragma unroll
    for (int i = 0; i < 4; i++) {
        long row = bm + tm + i;
        #pragma unroll
        for (int j = 0; j < 4; j++) {
            int col = bn + tn + j;
            if (col < N) {
                float v = acc[i][j];
                if (HASBIAS) v += bias[col];
                if (ACT == 1) v = gelu_exact(v);
                C[row * ldc + col] = v;
            }
        }
    }
}

// ---------------------------------------------------------------------------
__global__ __launch_bounds__(256)
void cvt_bf16(const float* __restrict__ s, bf16_t* __restrict__ d, long n)
{
    long i = ((long)blockIdx.x * 256 + threadIdx.x) * 4;
    if (i >= n) return;
    float4 v = *(const float4*)(s + i);
    d[i + 0] = __float2bfloat16(v.x);
    d[i + 1] = __float2bfloat16(v.y);
    d[i + 2] = __float2bfloat16(v.z);
    d[i + 3] = __float2bfloat16(v.w);
}

__global__ __launch_bounds__(256)
void cvt_bf16_pad(const float* __restrict__ s, bf16_t* __restrict__ d,
                  int rows_src, long total, int cols)
{
    long i = (long)blockIdx.x * 256 + threadIdx.x;
    if (i >= total) return;
    long r = i / cols;
    d[i] = __float2bfloat16(r < rows_src ? s[i] : 0.f);
}

// ---------------------------------------------------------------------------
// Causal depthwise conv (width 4) + SiLU, 4 channels per thread.
// ---------------------------------------------------------------------------
__global__ __launch_bounds__(256)
void conv_silu4(const bf16_t* __restrict__ zx, const float* __restrict__ cw,
                const float* __restrict__ cb, bf16_t* __restrict__ xBC, long count4)
{
    long i4 = (long)blockIdx.x * 256 + threadIdx.x;
    if (i4 >= count4) return;
    long idx = i4 * 4;
    int c = (int)(idx % CDIM);
    long t = idx / CDIM;
    int s = (int)(t % S);
    float v0 = cb[c], v1 = cb[c + 1], v2 = cb[c + 2], v3 = cb[c + 3];
    #pragma unroll
    for (int k = 0; k < 4; k++) {
        int sp = s + k - 3;
        if (sp >= 0) {
            const bf16_t* p = zx + (t + k - 3) * DIP + DI + c;
            unsigned long long u = *(const unsigned long long*)p;   // 4 bf16
            v0 += bfu2f((unsigned short)(u      )) * cw[(c + 0) * 4 + k];
            v1 += bfu2f((unsigned short)(u >> 16)) * cw[(c + 1) * 4 + k];
            v2 += bfu2f((unsigned short)(u >> 32)) * cw[(c + 2) * 4 + k];
            v3 += bfu2f((unsigned short)(u >> 48)) * cw[(c + 3) * 4 + k];
        }
    }
    v0 = v0 / (1.f + __expf(-v0));
    v1 = v1 / (1.f + __expf(-v1));
    v2 = v2 / (1.f + __expf(-v2));
    v3 = v3 / (1.f + __expf(-v3));
    unsigned long long o = (unsigned long long)f2bfu(v0)
                         | ((unsigned long long)f2bfu(v1) << 16)
                         | ((unsigned long long)f2bfu(v2) << 32)
                         | ((unsigned long long)f2bfu(v3) << 48);
    *(unsigned long long*)&xBC[idx] = o;
}

__global__ __launch_bounds__(256)
void dt_kernel(const float* __restrict__ raw, const float* __restrict__ dt_bias,
               float* __restrict__ dts, long count)
{
    long idx = (long)blockIdx.x * 256 + threadIdx.x;
    if (idx >= count) return;
    float x = raw[idx] + dt_bias[idx & 15];
    dts[idx] = (x > 20.f) ? x : log1pf(__expf(x));
}

// ---------------------------------------------------------------------------
// SSD states (MFMA), split in n-halves: block = (b,c,h,nh).
//   st[p][n0b+n] = sum_j X^T[p][j] * Bw^T[n][j]
// LDS ~35 KB -> 4 blocks/CU. Staging packed as 4-byte writes.
// ---------------------------------------------------------------------------
__global__ __launch_bounds__(256)
void ssd_states(const bf16_t* __restrict__ xBC, const float* __restrict__ dts,
                const float* __restrict__ A_log,
                float* __restrict__ st, float* __restrict__ acs_all,
                float* __restrict__ cdlog)
{
    const int bid = blockIdx.x;
    const int nh = bid & 1;
    const int h = (bid >> 1) & 15;
    const int c = (bid >> 5) & 15;
    const int b = bid >> 9;
    const int sbid = (b * NC + c) * NH + h;
    const int tid = threadIdx.x;
    const int lane = tid & 63;
    const int wave = tid >> 6;
    __shared__ float dtv[128];
    __shared__ float acs[128];
    __shared__ float wj[128];
    __shared__ bf16_t XT[64 * LP];
    __shared__ bf16_t BwT[64 * LP];
    const long t0 = (long)b * S + (long)c * CH;
    const float Ah = -__expf(A_log[h]);

    if (tid < 128) {
        float d = dts[(t0 + tid) * NH + h];
        dtv[tid] = d;
        acs[tid] = d * Ah;
    }
    __syncthreads();
    for (int off = 1; off < 128; off <<= 1) {
        float add = 0.f;
        if (tid < 128 && tid >= off) add = acs[tid - off];
        __syncthreads();
        if (tid < 128 && tid >= off) acs[tid] += add;
        __syncthreads();
    }
    const float el = acs[127];
    if (tid < 128) wj[tid] = __expf(el - acs[tid]) * dtv[tid];
    if (nh == 0) {
        if (tid < 128) acs_all[(long)sbid * 128 + tid] = acs[tid];
        if (tid == 0) cdlog[sbid] = el;
    }
    __syncthreads();

    const int n0b = nh * 64;
    // XT[p][j] packed pairs over j
    for (int i = tid; i < 4096; i += 256) {
        int p = i & 63, jp = (i >> 6) << 1;
        unsigned short a = *(const unsigned short*)&xBC[(t0 + jp) * CDIM + h * HD + p];
        unsigned short bb = *(const unsigned short*)&xBC[(t0 + jp + 1) * CDIM + h * HD + p];
        *(unsigned int*)&XT[p * LP + jp] = (unsigned)a | ((unsigned)bb << 16);
    }
    // BwT[n][j] packed pairs over j (scaled)
    for (int i = tid; i < 4096; i += 256) {
        int n = i & 63, jp = (i >> 6) << 1;
        float v0 = __bfloat162float(xBC[(t0 + jp) * CDIM + DI + n0b + n]) * wj[jp];
        float v1 = __bfloat162float(xBC[(t0 + jp + 1) * CDIM + DI + n0b + n]) * wj[jp + 1];
        *(unsigned int*)&BwT[n * LP + jp] = (unsigned)f2bfu(v0) | ((unsigned)f2bfu(v1) << 16);
    }
    __syncthreads();

    const int kq = lane >> 4;
    const int lr = lane & 15;
    const int p0w = (wave & 1) * 32;
    const int n0w = (wave >> 1) * 32;
    f32x4 acc[2][2];
    #pragma unroll
    for (int i = 0; i < 2; i++)
        #pragma unroll
        for (int j = 0; j < 2; j++) acc[i][j] = (f32x4){0.f, 0.f, 0.f, 0.f};
    #pragma unroll
    for (int t = 0; t < 4; t++) {
        short8 af[2], bfr[2];
        #pragma unroll
        for (int i = 0; i < 2; i++)
            af[i] = *(const short8*)&XT[(p0w + i * 16 + lr) * LP + t * 32 + kq * 8];
        #pragma unroll
        for (int j = 0; j < 2; j++)
            bfr[j] = *(const short8*)&BwT[(n0w + j * 16 + lr) * LP + t * 32 + kq * 8];
        #pragma unroll
        for (int i = 0; i < 2; i++)
            #pragma unroll
            for (int j = 0; j < 2; j++)
                acc[i][j] = __builtin_amdgcn_mfma_f32_16x16x32_bf16(af[i], bfr[j], acc[i][j], 0, 0, 0);
    }
    long base = (long)sbid * 8192;
    #pragma unroll
    for (int i = 0; i < 2; i++)
        #pragma unroll
        for (int j = 0; j < 2; j++) {
            int col = n0b + n0w + j * 16 + lr;
            #pragma unroll
            for (int r = 0; r < 4; r++) {
                int p = p0w + i * 16 + kq * 4 + r;
                st[base + p * 128 + col] = acc[i][j][r];
            }
        }
}

// ---------------------------------------------------------------------------
// Inter-chunk scan, q-sliced: grid (NB*NH, 4); each block owns 8 q-slices.
// ---------------------------------------------------------------------------
__global__ __launch_bounds__(256)
void ssd_scan(float* __restrict__ st, const float* __restrict__ cdlog)
{
    const int h = blockIdx.x & 15;
    const int b = blockIdx.x >> 4;
    const int q0 = blockIdx.y * 8;
    const int tid = threadIdx.x;
    float prev[8];
    #pragma unroll
    for (int q = 0; q < 8; q++) prev[q] = 0.f;
    for (int c = 0; c < NC; c++) {
        int bc = (b * NC + c) * NH + h;
        float cd = __expf(cdlog[bc]);
        long base = (long)bc * 8192 + (long)q0 * 256;
        #pragma unroll
        for (int q = 0; q < 8; q++) {
            long idx = base + (long)q * 256 + tid;
            float v = st[idx];
            st[idx] = prev[q];
            prev[q] = cd * prev[q] + v;
        }
    }
}

// ---------------------------------------------------------------------------
// SSD output (MFMA, fused diag+off+D*x), split in i-halves: block=(b,c,h,ih).
//   phase 1: A=W[i][j] (G*decay*dt, masked), B=X^T[p][j]  (K=128)
//   phase 2: A=e^{acs_i} C[i][n], B=prev[p][n]            (K=128)
//   y[i][p] = acc + D_h x[i][p]   (bf16 out)
// LDS ~35 KB. G is bf16.
// ---------------------------------------------------------------------------
__global__ __launch_bounds__(256)
void ssd_out(const bf16_t* __restrict__ xBC, const float* __restrict__ dts,
             const bf16_t* __restrict__ G, const float* __restrict__ st,
             const float* __restrict__ acs_all, const float* __restrict__ D_head,
             bf16_t* __restrict__ y)
{
    const int bid = blockIdx.x;
    const int ih = bid & 1;
    const int h = (bid >> 1) & 15;
    const int c = (bid >> 5) & 15;
    const int b = bid >> 9;
    const int sbid = (b * NC + c) * NH + h;
    const int tid = threadIdx.x;
    const int lane = tid & 63;
    const int wave = tid >> 6;
    __shared__ float dtv[128];
    __shared__ float acs[128];
    __shared__ float eacs[64];
    __shared__ bf16_t Abuf[64 * LP];
    __shared__ bf16_t Bbuf[64 * LP];
    const long t0 = (long)b * S + (long)c * CH;
    const int m0b = ih * 64;

    if (tid < 128) {
        dtv[tid] = dts[(t0 + tid) * NH + h];
        acs[tid] = acs_all[(long)sbid * 128 + tid];
    }
    __syncthreads();
    if (tid < 64) eacs[tid] = __expf(acs[m0b + tid]);

    // phase-1 staging: W rows (block's i-half) packed pairs over k
    const bf16_t* Gb = G + (long)(b * NC + c) * 128 * 128;
    for (int i = tid; i < 4096; i += 256) {
        int rl = i >> 6, kp = (i & 63) << 1;
        int grow = m0b + rl;
        unsigned int g2 = *(const unsigned int*)&Gb[grow * 128 + kp];
        float w0 = (kp     <= grow) ? bfu2f((unsigned short)(g2      )) * __expf(acs[grow] - acs[kp    ]) * dtv[kp    ] : 0.f;
        float w1 = (kp + 1 <= grow) ? bfu2f((unsigned short)(g2 >> 16)) * __expf(acs[grow] - acs[kp + 1]) * dtv[kp + 1] : 0.f;
        *(unsigned int*)&Abuf[rl * LP + kp] = (unsigned)f2bfu(w0) | ((unsigned)f2bfu(w1) << 16);
    }
    // X^T[p][j] full j, packed pairs
    for (int i = tid; i < 4096; i += 256) {
        int p = i & 63, jp = (i >> 6) << 1;
        unsigned short a = *(const unsigned short*)&xBC[(t0 + jp) * CDIM + h * HD + p];
        unsigned short bb = *(const unsigned short*)&xBC[(t0 + jp + 1) * CDIM + h * HD + p];
        *(unsigned int*)&Bbuf[p * LP + jp] = (unsigned)a | ((unsigned)bb << 16);
    }
    __syncthreads();

    const int kq = lane >> 4;
    const int lr = lane & 15;
    const int m0w = (wave & 1) * 32;
    const int p0 = (wave >> 1) * 32;
    f32x4 acc[2][2];
    #pragma unroll
    for (int i = 0; i < 2; i++)
        #pragma unroll
        for (int j = 0; j < 2; j++) acc[i][j] = (f32x4){0.f, 0.f, 0.f, 0.f};

    #pragma unroll
    for (int t = 0; t < 4; t++) {
        short8 af[2], bfr[2];
        #pragma unroll
        for (int i = 0; i < 2; i++)
            af[i] = *(const short8*)&Abuf[(m0w + i * 16 + lr) * LP + t * 32 + kq * 8];
        #pragma unroll
        for (int j = 0; j < 2; j++)
            bfr[j] = *(const short8*)&Bbuf[(p0 + j * 16 + lr) * LP + t * 32 + kq * 8];
        #pragma unroll
        for (int i = 0; i < 2; i++)
            #pragma unroll
            for (int j = 0; j < 2; j++)
                acc[i][j] = __builtin_amdgcn_mfma_f32_16x16x32_bf16(af[i], bfr[j], acc[i][j], 0, 0, 0);
    }
    // D*x: x[i][p] from Bbuf (X^T, j index = GLOBAL time) before overwrite
    const float Dh = D_head[h];
    float dx[2][2][4];
    #pragma unroll
    for (int i = 0; i < 2; i++)
        #pragma unroll
        for (int j = 0; j < 2; j++) {
            int col = p0 + j * 16 + lr;
            #pragma unroll
            for (int r = 0; r < 4; r++) {
                int rl = m0w + i * 16 + kq * 4 + r;
                dx[i][j][r] = Dh * __bfloat162float(Bbuf[col * LP + m0b + rl]);
            }
        }
    __syncthreads();

    // phase-2 staging: A = e^{acs_i} C (block's i-half), B = prev[p][n]
    for (int i = tid; i < 4096; i += 256) {
        int rl = i >> 6, np = (i & 63) << 1;
        unsigned int c2 = *(const unsigned int*)&xBC[(t0 + m0b + rl) * CDIM + DI + DSTATE + np];
        float e = eacs[rl];
        float v0 = e * bfu2f((unsigned short)(c2      ));
        float v1 = e * bfu2f((unsigned short)(c2 >> 16));
        *(unsigned int*)&Abuf[rl * LP + np] = (unsigned)f2bfu(v0) | ((unsigned)f2bfu(v1) << 16);
    }
    for (int i = tid; i < 4096; i += 256) {
        int p = i >> 6, np = (i & 63) << 1;
        float2 v = *(const float2*)&st[(long)sbid * 8192 + p * 128 + np];
        *(unsigned int*)&Bbuf[p * LP + np] = (unsigned)f2bfu(v.x) | ((unsigned)f2bfu(v.y) << 16);
    }
    __syncthreads();

    #pragma unroll
    for (int t = 0; t < 4; t++) {
        short8 af[2], bfr[2];
        #pragma unroll
        for (int i = 0; i < 2; i++)
            af[i] = *(const short8*)&Abuf[(m0w + i * 16 + lr) * LP + t * 32 + kq * 8];
        #pragma unroll
        for (int j = 0; j < 2; j++)
            bfr[j] = *(const short8*)&Bbuf[(p0 + j * 16 + lr) * LP + t * 32 + kq * 8];
        #pragma unroll
        for (int i = 0; i < 2; i++)
            #pragma unroll
            for (int j = 0; j < 2; j++)
                acc[i][j] = __builtin_amdgcn_mfma_f32_16x16x32_bf16(af[i], bfr[j], acc[i][j], 0, 0, 0);
    }

    #pragma unroll
    for (int i = 0; i < 2; i++)
        #pragma unroll
        for (int j = 0; j < 2; j++) {
            int col = p0 + j * 16 + lr;
            #pragma unroll
            for (int r = 0; r < 4; r++) {
                int rl = m0w + i * 16 + kq * 4 + r;
                y[(t0 + m0b + rl) * DI + h * HD + col] = __float2bfloat16(acc[i][j][r] + dx[i][j][r]);
            }
        }
}

// ---------------------------------------------------------------------------
__global__ __launch_bounds__(256)
void gated_rms(const bf16_t* __restrict__ y, const bf16_t* __restrict__ zx,
               const float* __restrict__ norm_w, bf16_t* __restrict__ yn)
{
    const long t = blockIdx.x;
    const int tid = threadIdx.x;
    float g[4];
    float ss = 0.f, dummy = 0.f;
    #pragma unroll
    for (int q = 0; q < 4; q++) {
        int d = tid + q * 256;
        float zv = __bfloat162float(zx[t * DIP + d]);
        float yv = __bfloat162float(y[t * DI + d]);
        float gv = yv * (zv / (1.f + __expf(-zv)));
        g[q] = gv;
        ss += gv * gv;
    }
    block_sum2(ss, dummy);
    float scale = rsqrtf(ss * (1.f / DI) + EPS);
    #pragma unroll
    for (int q = 0; q < 4; q++) {
        int d = tid + q * 256;
        yn[t * DI + d] = __float2bfloat16(g[q] * scale * norm_w[d]);
    }
}

// ---------------------------------------------------------------------------
__global__ __launch_bounds__(256)
void add_ln(const float* __restrict__ x, const float* __restrict__ r,
            const float* __restrict__ w, const float* __restrict__ bpar,
            float* __restrict__ o32, bf16_t* __restrict__ o16)
{
    const long t = blockIdx.x;
    const int tid = threadIdx.x;
    float v[2];
    float s = 0.f, s2 = 0.f;
    #pragma unroll
    for (int q = 0; q < 2; q++) {
        int d = tid + q * 256;
        float vv = x[t * DM + d] + r[t * DM + d];
        v[q] = vv;
        s += vv;
        s2 += vv * vv;
    }
    block_sum2(s, s2);
    float mean = s * (1.f / DM);
    float var = s2 * (1.f / DM) - mean * mean;
    float inv = rsqrtf(var + EPS);
    #pragma unroll
    for (int q = 0; q < 2; q++) {
        int d = tid + q * 256;
        float o = (v[q] - mean) * inv * w[d] + bpar[d];
        o32[t * DM + d] = o;
        o16[t * DM + d] = __float2bfloat16(o);
    }
}

// ---------------------------------------------------------------------------

extern "C" void kernel_launch(void* const* d_in, const int* in_sizes, int n_in,
                              void* d_out, int out_size, void* d_ws, size_t ws_size,
                              hipStream_t stream)
{
    const float* tgt       = (const float*)d_in[0];
    const float* in_proj_w = (const float*)d_in[5];
    const float* conv_w    = (const float*)d_in[6];
    const float* conv_b    = (const float*)d_in[7];
    const float* dt_bias   = (const float*)d_in[8];
    const float* A_log     = (const float*)d_in[9];
    const float* D_head    = (const float*)d_in[10];
    const float* norm_w    = (const float*)d_in[11];
    const float* out_proj_w= (const float*)d_in[12];
    const float* norm1_w   = (const float*)d_in[13];
    const float* norm1_b   = (const float*)d_in[14];
    const float* w1        = (const float*)d_in[15];
    const float* b1        = (const float*)d_in[16];
    const float* w2        = (const float*)d_in[17];
    const float* b2        = (const float*)d_in[18];
    const float* norm3_w   = (const float*)d_in[19];
    const float* norm3_b   = (const float*)d_in[20];
    float* out = (float*)d_out;

    float* ws = (float*)d_ws;

    const size_t SZ_INW  = (size_t)DIPP * DM / 2;
    const size_t SZ_OUTW = (size_t)DM * DI / 2;
    const size_t SZ_W1   = (size_t)FF * DM / 2;
    const size_t SZ_W2   = (size_t)DM * FF / 2;
    size_t wo = 0;
    bf16_t* inW  = (bf16_t*)(ws + wo); wo += SZ_INW;
    bf16_t* outW = (bf16_t*)(ws + wo); wo += SZ_OUTW;
    bf16_t* w1b  = (bf16_t*)(ws + wo); wo += SZ_W1;
    bf16_t* w2b  = (bf16_t*)(ws + wo); wo += SZ_W2;
    const size_t WB = wo;

    const size_t PB = (size_t)S * DM / 2            // tgt_bf
                    + (size_t)S * DIP / 2           // zx_bf
                    + (size_t)S * NH                // dts_raw
                    + (size_t)S * NH                // dts
                    + (size_t)S * CDIM / 2          // xBC_bf
                    + (size_t)NC * 128 * 128 / 2    // G (bf16)
                    + (size_t)NC * NH * 128         // acs
                    + (size_t)NC * NH               // cdl
                    + (size_t)S * DI                // y region (used as bf16 then f32 t2/h1)
                    + (size_t)S * DI;               // st
    int NB = 0;
    for (int nb = 8; nb >= 1; nb >>= 1) {
        if (ws_size >= (WB + (size_t)nb * PB) * sizeof(float)) { NB = nb; break; }
    }
    if (NB == 0) return;

    {
        long n = (long)DIPP * DM;
        cvt_bf16_pad<<<(n + 255) / 256, 256, 0, stream>>>(in_proj_w, inW, DIP, n, DM);
        n = (long)DM * DI;
        cvt_bf16<<<(n / 4 + 255) / 256, 256, 0, stream>>>(out_proj_w, outW, n);
        n = (long)FF * DM;
        cvt_bf16<<<(n / 4 + 255) / 256, 256, 0, stream>>>(w1, w1b, n);
        n = (long)DM * FF;
        cvt_bf16<<<(n / 4 + 255) / 256, 256, 0, stream>>>(w2, w2b, n);
    }

    for (int b0 = 0; b0 < BB; b0 += NB) {
        const long Tg = (long)NB * S;
        size_t o = WB;
        bf16_t* tgt_bf = (bf16_t*)(ws + o); o += (size_t)Tg * DM / 2;
        bf16_t* zx     = (bf16_t*)(ws + o); o += (size_t)Tg * DIP / 2;
        float*  dts_raw= ws + o;            o += (size_t)Tg * NH;
        float*  dts    = ws + o;            o += (size_t)Tg * NH;
        bf16_t* xBC    = (bf16_t*)(ws + o); o += (size_t)Tg * CDIM / 2;
        bf16_t* Gbuf   = (bf16_t*)(ws + o); o += (size_t)NB * NC * 128 * 128 / 2;
        float*  acs    = ws + o;            o += (size_t)NB * NC * NH * 128;
        float*  cdl    = ws + o;            o += (size_t)NB * NC * NH;
        float*  ybuf   = ws + o;            o += (size_t)Tg * DI;
        float*  st     = ws + o;            o += (size_t)Tg * DI;

        bf16_t* ybf = (bf16_t*)ybuf;                     // y as bf16
        bf16_t* yn  = (bf16_t*)st;                       // after ssd_out
        float*  t2  = ybuf;                              // after gated_rms
        float*  tb  = (float*)zx;                        // t f32
        bf16_t* tbb = (bf16_t*)(((float*)zx) + Tg * DM); // t bf16
        bf16_t* h1  = (bf16_t*)ybuf;                     // after add_ln1
        float*  fb  = (float*)xBC;                       // after ssd_out
        bf16_t* dummy16 = tbb;

        const float* tgt_g = tgt + (long)b0 * S * DM;
        float* out_g = out + (long)b0 * S * DM;

        cvt_bf16<<<((Tg * DM) / 4 + 255) / 256, 256, 0, stream>>>(tgt_g, tgt_bf, Tg * DM);
        mfma_gemm<128, 0, false, true><<<dim3(DIPP / 128, Tg / 128, 1), 256, 0, stream>>>(
            tgt_bf, inW, nullptr, zx, DIP, DM, DM, DM, DIP, 0, 0, 0);
        gemm_kernel<0, false><<<dim3(1, Tg / 64, 1), 256, 0, stream>>>(
            tgt_g, in_proj_w + (long)(DI + CDIM) * DM, nullptr, dts_raw,
            Tg, NH, DM, DM, DM, NH, 0, 0, 0);
        dt_kernel<<<(Tg * NH) / 256, 256, 0, stream>>>(dts_raw, dt_bias, dts, Tg * NH);
        conv_silu4<<<(Tg * CDIM / 4) / 256, 256, 0, stream>>>(zx, conv_w, conv_b, xBC, Tg * CDIM / 4);
        // G = C @ B^T per chunk (bf16 out)
        mfma_gemm<128, 0, false, true><<<dim3(1, 1, NB * NC), 256, 0, stream>>>(
            xBC + DI + DSTATE, xBC + DI, nullptr, Gbuf,
            128, DSTATE, CDIM, CDIM, 128,
            (long)CH * CDIM, (long)CH * CDIM, (long)128 * 128);
        // SSD
        ssd_states<<<NB * NC * NH * 2, 256, 0, stream>>>(xBC, dts, A_log, st, acs, cdl);
        ssd_scan<<<dim3(NB * NH, 4), 256, 0, stream>>>(st, cdl);
        ssd_out<<<NB * NC * NH * 2, 256, 0, stream>>>(xBC, dts, Gbuf, st, acs, D_head, ybf);
        gated_rms<<<Tg, 256, 0, stream>>>(ybf, zx, norm_w, yn);
        mfma_gemm<64, 0, false, false><<<dim3(DM / 128, Tg / 64, 1), 256, 0, stream>>>(
            yn, outW, nullptr, t2, DM, DI, DI, DI, DM, 0, 0, 0);
        add_ln<<<Tg, 256, 0, stream>>>(tgt_g, t2, norm1_w, norm1_b, tb, tbb);
        mfma_gemm<128, 1, true, true><<<dim3(FF / 128, Tg / 128, 1), 256, 0, stream>>>(
            tbb, w1b, b1, h1, FF, DM, DM, DM, FF, 0, 0, 0);
        mfma_gemm<64, 0, true, false><<<dim3(DM / 128, Tg / 64, 1), 256, 0, stream>>>(
            h1, w2b, b2, fb, DM, FF, FF, FF, DM, 0, 0, 0);
        add_ln<<<Tg, 256, 0, stream>>>(tb, fb, norm3_w, norm3_b, out_g, dummy16);
    }
}

// Round 7
// 839.051 us; speedup vs baseline: 2.8791x; 1.1480x over previous
//
#include <hip/hip_runtime.h>
#include <hip/hip_bf16.h>
#include <math.h>

// ---------------------------------------------------------------------------
// Mamba2 layer (round 6):
//  - conv rewritten: register rolling-window, 1 thread = 4 channels x 16 time
//    steps, 19 independent up-front loads (MLP), no integer division
//  - dt softplus fused into the dt GEMM epilogue (ACT=2)
//  - gated_rms / add_ln vectorized to 8B/lane; add_ln 2 rows/block;
//    final add_ln skips the unused bf16 copy
// ---------------------------------------------------------------------------

namespace {
constexpr int BB = 8;
constexpr int S = 2048;
constexpr int DM = 512;
constexpr int DIP = 2320;
constexpr int DIPP = 2432;       // padded to 19*128
constexpr int DI = 1024;
constexpr int CDIM = 1280;
constexpr int NH = 16;
constexpr int HD = 64;
constexpr int DSTATE = 128;
constexpr int CH = 128;
constexpr int NC = S / CH;       // 16
constexpr int FF = 2048;
constexpr float EPS = 1e-5f;
constexpr int LP = 132;          // padded K stride for SSD LDS tiles
}

using bf16_t = __hip_bfloat16;
typedef __attribute__((ext_vector_type(8))) short short8;
typedef __attribute__((ext_vector_type(4))) float f32x4;

__device__ __forceinline__ float gelu_exact(float x) {
    return 0.5f * x * (1.0f + erff(x * 0.7071067811865476f));
}
__device__ __forceinline__ unsigned short f2bfu(float f) {
    bf16_t b = __float2bfloat16(f);
    return *(unsigned short*)&b;
}
__device__ __forceinline__ float bfu2f(unsigned short u) {
    union { unsigned int i; float f; } v; v.i = (unsigned)u << 16; return v.f;
}

__device__ __forceinline__ void block_sum2(float& a, float& b) {
    #pragma unroll
    for (int o = 32; o > 0; o >>= 1) {
        a += __shfl_down(a, o, 64);
        b += __shfl_down(b, o, 64);
    }
    __shared__ float sa[4], sb[4];
    int w = threadIdx.x >> 6;
    if ((threadIdx.x & 63) == 0) { sa[w] = a; sb[w] = b; }
    __syncthreads();
    a = sa[0] + sa[1] + sa[2] + sa[3];
    b = sb[0] + sb[1] + sb[2] + sb[3];
}

// ---------------------------------------------------------------------------
// bf16 MFMA GEMM, register-staged + LDS double-buffered (round 3).
// ---------------------------------------------------------------------------
template <int BM, int ACT, bool HASBIAS, bool OUTBF>
__global__ __launch_bounds__(256)
void mfma_gemm(const bf16_t* __restrict__ A, const bf16_t* __restrict__ W,
               const float* __restrict__ bias, void* __restrict__ Cout,
               int N, int K, int lda, int ldw, int ldc,
               long batchA, long batchW, long batchC)
{
    A += (long)blockIdx.z * batchA;
    W += (long)blockIdx.z * batchW;
    constexpr int ACH = BM / 64;
    constexpr int NJ = (BM == 128) ? 4 : 2;
    __shared__ bf16_t As[2][BM * 32];
    __shared__ bf16_t Ws[2][4096];
    const int tid = threadIdx.x;
    const int lane = tid & 63;
    const int wave = tid >> 6;
    const long bm = (long)blockIdx.y * BM;
    const int bn = blockIdx.x * 128;

    const int rA = tid & (BM - 1);
    const int qA = tid / BM;
    const int rW = tid & 127;
    const int qW = tid >> 7;
    const bf16_t* Ag = A + (bm + rA) * (long)lda + qA * 8;
    const bf16_t* Wg = W + ((long)bn + rW) * (long)ldw + qW * 8;
    const int laoff0 = (qA * BM + rA) * 8;
    const int laoff1 = ((qA + 2) * BM + rA) * 8;
    const int lwoff0 = (qW * 128 + rW) * 8;
    const int lwoff1 = ((qW + 2) * 128 + rW) * 8;

    const int kq = lane >> 4;
    const int lr = lane & 15;
    const int wm = (BM == 128) ? (wave & 1) * 64 : 0;
    const int wn = (BM == 128) ? (wave >> 1) * 64 : wave * 32;

    f32x4 acc[4][NJ];
    #pragma unroll
    for (int i = 0; i < 4; i++)
        #pragma unroll
        for (int j = 0; j < NJ; j++) acc[i][j] = (f32x4){0.f, 0.f, 0.f, 0.f};

    short8 ra0, ra1, rw0, rw1;
    ra0 = *(const short8*)Ag;
    if (ACH == 2) ra1 = *(const short8*)(Ag + 16);
    rw0 = *(const short8*)Wg;
    rw1 = *(const short8*)(Wg + 16);
    *(short8*)&As[0][laoff0] = ra0;
    if (ACH == 2) *(short8*)&As[0][laoff1] = ra1;
    *(short8*)&Ws[0][lwoff0] = rw0;
    *(short8*)&Ws[0][lwoff1] = rw1;

    const int nt = K / 32;
    for (int t = 0; t < nt; t++) {
        const int cur = t & 1, nxt = cur ^ 1;
        if (t + 1 < nt) {
            const int ko = (t + 1) * 32;
            ra0 = *(const short8*)(Ag + ko);
            if (ACH == 2) ra1 = *(const short8*)(Ag + ko + 16);
            rw0 = *(const short8*)(Wg + ko);
            rw1 = *(const short8*)(Wg + ko + 16);
        }
        __syncthreads();
        short8 af[4], bfr[NJ];
        #pragma unroll
        for (int i = 0; i < 4; i++)
            af[i] = *(const short8*)&As[cur][(kq * BM + wm + i * 16 + lr) * 8];
        #pragma unroll
        for (int j = 0; j < NJ; j++)
            bfr[j] = *(const short8*)&Ws[cur][(kq * 128 + wn + j * 16 + lr) * 8];
        #pragma unroll
        for (int i = 0; i < 4; i++)
            #pragma unroll
            for (int j = 0; j < NJ; j++)
                acc[i][j] = __builtin_amdgcn_mfma_f32_16x16x32_bf16(af[i], bfr[j], acc[i][j], 0, 0, 0);
        if (t + 1 < nt) {
            *(short8*)&As[nxt][laoff0] = ra0;
            if (ACH == 2) *(short8*)&As[nxt][laoff1] = ra1;
            *(short8*)&Ws[nxt][lwoff0] = rw0;
            *(short8*)&Ws[nxt][lwoff1] = rw1;
        }
    }

    #pragma unroll
    for (int i = 0; i < 4; i++) {
        #pragma unroll
        for (int j = 0; j < NJ; j++) {
            int col = bn + wn + j * 16 + lr;
            if (col < N) {
                float bv = HASBIAS ? bias[col] : 0.f;
                #pragma unroll
                for (int r = 0; r < 4; r++) {
                    long row = bm + wm + i * 16 + kq * 4 + r;
                    float v = acc[i][j][r] + bv;
                    if (ACT == 1) v = gelu_exact(v);
                    if (OUTBF) ((bf16_t*)Cout)[row * (long)ldc + col + blockIdx.z * batchC] = __float2bfloat16(v);
                    else       ((float*)Cout)[row * (long)ldc + col + blockIdx.z * batchC] = v;
                }
            }
        }
    }
}

// ---------------------------------------------------------------------------
// f32 GEMM for the tiny dt projection (N=16). ACT: 0=none, 2=softplus.
// ---------------------------------------------------------------------------
template <int ACT, bool HASBIAS>
__global__ __launch_bounds__(256)
void gemm_kernel(const float* __restrict__ A, const float* __restrict__ W,
                 const float* __restrict__ bias, float* __restrict__ C,
                 int M, int N, int K, int lda, int ldw, int ldc,
                 long batchA, long batchW, long batchC)
{
    A += (long)blockIdx.z * batchA;
    W += (long)blockIdx.z * batchW;
    C += (long)blockIdx.z * batchC;
    __shared__ __align__(16) float Asm[16][68];
    __shared__ __align__(16) float Wsm[16][68];
    const int tid = threadIdx.x;
    const int bm = blockIdx.y * 64;
    const int bn = blockIdx.x * 64;
    const int tm = (tid & 15) * 4;
    const int tn = (tid >> 4) * 4;
    const int lr = tid >> 2;
    const int lk = (tid & 3) * 4;
    const float* Ap = A + (long)(bm + lr) * lda + lk;
    const float* Wp = W + (long)(bn + lr) * ldw + lk;
    const bool wv_ok = (bn + lr) < N;
    float acc[4][4];
    #pragma unroll
    for (int i = 0; i < 4; i++)
        #pragma unroll
        for (int j = 0; j < 4; j++) acc[i][j] = 0.f;

    for (int k0 = 0; k0 < K; k0 += 16) {
        float4 av = *(const float4*)(Ap + k0);
        float4 wv = wv_ok ? *(const float4*)(Wp + k0) : make_float4(0.f, 0.f, 0.f, 0.f);
        Asm[lk + 0][lr] = av.x; Asm[lk + 1][lr] = av.y;
        Asm[lk + 2][lr] = av.z; Asm[lk + 3][lr] = av.w;
        Wsm[lk + 0][lr] = wv.x; Wsm[lk + 1][lr] = wv.y;
        Wsm[lk + 2][lr] = wv.z; Wsm[lk + 3][lr] = wv.w;
        __syncthreads();
        #pragma unroll
        for (int k = 0; k < 16; k++) {
            float4 a = *(const float4*)&Asm[k][tm];
            float4 w = *(const float4*)&Wsm[k][tn];
            acc[0][0] += a.x * w.x; acc[0][1] += a.x * w.y; acc[0][2] += a.x * w.z; acc[0][3] += a.x * w.w;
            acc[1][0] += a.y * w.x; acc[1][1] += a.y * w.y; acc[1][2] += a.y * w.z; acc[1][3] += a.y * w.w;
            acc[2][0] += a.z * w.x; acc[2][1] += a.z * w.y; acc[2][2] += a.z * w.z; acc[2][3] += a.z * w.w;
            acc[3][0] += a.w * w.x; acc[3][1] += a.w * w.y; acc[3][2] += a.w * w.z; acc[3][3] += a.w * w.w;
        }
        __syncthreads();
    }
    #pragma unroll
    for (int i = 0; i < 4; i++) {
        long row = bm + tm + i;
        #pragma unroll
        for (int j = 0; j < 4; j++) {
            int col = bn + tn + j;
            if (col < N) {
                float v = acc[i][j];
                if (HASBIAS) v += bias[col];
                if (ACT == 1) v = gelu_exact(v);
                if (ACT == 2) v = (v > 20.f) ? v : log1pf(__expf(v));
                C[row * ldc + col] = v;
            }
        }
    }
}

// ---------------------------------------------------------------------------
__global__ __launch_bounds__(256)
void cvt_bf16(const float* __restrict__ s, bf16_t* __restrict__ d, long n)
{
    long i = ((long)blockIdx.x * 256 + threadIdx.x) * 4;
    if (i >= n) return;
    float4 v = *(const float4*)(s + i);
    d[i + 0] = __float2bfloat16(v.x);
    d[i + 1] = __float2bfloat16(v.y);
    d[i + 2] = __float2bfloat16(v.z);
    d[i + 3] = __float2bfloat16(v.w);
}

__global__ __launch_bounds__(256)
void cvt_bf16_pad(const float* __restrict__ s, bf16_t* __restrict__ d,
                  int rows_src, long total, int cols)
{
    long i = (long)blockIdx.x * 256 + threadIdx.x;
    if (i >= total) return;
    long r = i / cols;
    d[i] = __float2bfloat16(r < rows_src ? s[i] : 0.f);
}

// ---------------------------------------------------------------------------
// Causal depthwise conv (width 4) + SiLU, register rolling-window.
// Thread = one 4-channel quad x 16 time steps; 19 up-front independent 8B
// loads (3-row halo). Grid (CDIM/256, S/64, NB); wave w covers times
// [by*64 + w*16, +16). No integer division.
// ---------------------------------------------------------------------------
__global__ __launch_bounds__(256)
void conv_silu_t16(const bf16_t* __restrict__ zx, const float* __restrict__ cw,
                   const float* __restrict__ cb, bf16_t* __restrict__ xBC)
{
    const int quad = blockIdx.x * 64 + (threadIdx.x & 63);   // 0..319
    const int wv = threadIdx.x >> 6;
    const int c = quad * 4;
    const int s0 = blockIdx.y * 64 + wv * 16;
    const long t0 = (long)blockIdx.z * S + s0;

    float wgt[4][4];
    #pragma unroll
    for (int cc = 0; cc < 4; cc++)
        #pragma unroll
        for (int k = 0; k < 4; k++) wgt[cc][k] = cw[(c + cc) * 4 + k];
    float bias[4];
    #pragma unroll
    for (int cc = 0; cc < 4; cc++) bias[cc] = cb[c + cc];

    unsigned long long rows[19];
    #pragma unroll
    for (int i = 0; i < 19; i++) {
        int s = s0 + i - 3;
        rows[i] = (s >= 0) ? *(const unsigned long long*)&zx[(t0 + i - 3) * DIP + DI + c] : 0ULL;
    }
    #pragma unroll
    for (int i = 0; i < 16; i++) {
        float v[4];
        #pragma unroll
        for (int cc = 0; cc < 4; cc++) v[cc] = bias[cc];
        #pragma unroll
        for (int k = 0; k < 4; k++) {
            unsigned long long u = rows[i + k];
            v[0] += bfu2f((unsigned short)(u      )) * wgt[0][k];
            v[1] += bfu2f((unsigned short)(u >> 16)) * wgt[1][k];
            v[2] += bfu2f((unsigned short)(u >> 32)) * wgt[2][k];
            v[3] += bfu2f((unsigned short)(u >> 48)) * wgt[3][k];
        }
        unsigned long long o = 0;
        #pragma unroll
        for (int cc = 0; cc < 4; cc++) {
            float sv = v[cc] / (1.f + __expf(-v[cc]));
            o |= (unsigned long long)f2bfu(sv) << (16 * cc);
        }
        *(unsigned long long*)&xBC[(t0 + i) * (long)CDIM + c] = o;
    }
}

// ---------------------------------------------------------------------------
// SSD states (MFMA), split in n-halves: block = (b,c,h,nh).
// ---------------------------------------------------------------------------
__global__ __launch_bounds__(256)
void ssd_states(const bf16_t* __restrict__ xBC, const float* __restrict__ dts,
                const float* __restrict__ A_log,
                float* __restrict__ st, float* __restrict__ acs_all,
                float* __restrict__ cdlog)
{
    const int bid = blockIdx.x;
    const int nh = bid & 1;
    const int h = (bid >> 1) & 15;
    const int c = (bid >> 5) & 15;
    const int b = bid >> 9;
    const int sbid = (b * NC + c) * NH + h;
    const int tid = threadIdx.x;
    const int lane = tid & 63;
    const int wave = tid >> 6;
    __shared__ float dtv[128];
    __shared__ float acs[128];
    __shared__ float wj[128];
    __shared__ bf16_t XT[64 * LP];
    __shared__ bf16_t BwT[64 * LP];
    const long t0 = (long)b * S + (long)c * CH;
    const float Ah = -__expf(A_log[h]);

    if (tid < 128) {
        float d = dts[(t0 + tid) * NH + h];
        dtv[tid] = d;
        acs[tid] = d * Ah;
    }
    __syncthreads();
    for (int off = 1; off < 128; off <<= 1) {
        float add = 0.f;
        if (tid < 128 && tid >= off) add = acs[tid - off];
        __syncthreads();
        if (tid < 128 && tid >= off) acs[tid] += add;
        __syncthreads();
    }
    const float el = acs[127];
    if (tid < 128) wj[tid] = __expf(el - acs[tid]) * dtv[tid];
    if (nh == 0) {
        if (tid < 128) acs_all[(long)sbid * 128 + tid] = acs[tid];
        if (tid == 0) cdlog[sbid] = el;
    }
    __syncthreads();

    const int n0b = nh * 64;
    for (int i = tid; i < 4096; i += 256) {
        int p = i & 63, jp = (i >> 6) << 1;
        unsigned short a = *(const unsigned short*)&xBC[(t0 + jp) * CDIM + h * HD + p];
        unsigned short bb = *(const unsigned short*)&xBC[(t0 + jp + 1) * CDIM + h * HD + p];
        *(unsigned int*)&XT[p * LP + jp] = (unsigned)a | ((unsigned)bb << 16);
    }
    for (int i = tid; i < 4096; i += 256) {
        int n = i & 63, jp = (i >> 6) << 1;
        float v0 = __bfloat162float(xBC[(t0 + jp) * CDIM + DI + n0b + n]) * wj[jp];
        float v1 = __bfloat162float(xBC[(t0 + jp + 1) * CDIM + DI + n0b + n]) * wj[jp + 1];
        *(unsigned int*)&BwT[n * LP + jp] = (unsigned)f2bfu(v0) | ((unsigned)f2bfu(v1) << 16);
    }
    __syncthreads();

    const int kq = lane >> 4;
    const int lr = lane & 15;
    const int p0w = (wave & 1) * 32;
    const int n0w = (wave >> 1) * 32;
    f32x4 acc[2][2];
    #pragma unroll
    for (int i = 0; i < 2; i++)
        #pragma unroll
        for (int j = 0; j < 2; j++) acc[i][j] = (f32x4){0.f, 0.f, 0.f, 0.f};
    #pragma unroll
    for (int t = 0; t < 4; t++) {
        short8 af[2], bfr[2];
        #pragma unroll
        for (int i = 0; i < 2; i++)
            af[i] = *(const short8*)&XT[(p0w + i * 16 + lr) * LP + t * 32 + kq * 8];
        #pragma unroll
        for (int j = 0; j < 2; j++)
            bfr[j] = *(const short8*)&BwT[(n0w + j * 16 + lr) * LP + t * 32 + kq * 8];
        #pragma unroll
        for (int i = 0; i < 2; i++)
            #pragma unroll
            for (int j = 0; j < 2; j++)
                acc[i][j] = __builtin_amdgcn_mfma_f32_16x16x32_bf16(af[i], bfr[j], acc[i][j], 0, 0, 0);
    }
    long base = (long)sbid * 8192;
    #pragma unroll
    for (int i = 0; i < 2; i++)
        #pragma unroll
        for (int j = 0; j < 2; j++) {
            int col = n0b + n0w + j * 16 + lr;
            #pragma unroll
            for (int r = 0; r < 4; r++) {
                int p = p0w + i * 16 + kq * 4 + r;
                st[base + p * 128 + col] = acc[i][j][r];
            }
        }
}

// ---------------------------------------------------------------------------
__global__ __launch_bounds__(256)
void ssd_scan(float* __restrict__ st, const float* __restrict__ cdlog)
{
    const int h = blockIdx.x & 15;
    const int b = blockIdx.x >> 4;
    const int q0 = blockIdx.y * 8;
    const int tid = threadIdx.x;
    float prev[8];
    #pragma unroll
    for (int q = 0; q < 8; q++) prev[q] = 0.f;
    for (int c = 0; c < NC; c++) {
        int bc = (b * NC + c) * NH + h;
        float cd = __expf(cdlog[bc]);
        long base = (long)bc * 8192 + (long)q0 * 256;
        #pragma unroll
        for (int q = 0; q < 8; q++) {
            long idx = base + (long)q * 256 + tid;
            float v = st[idx];
            st[idx] = prev[q];
            prev[q] = cd * prev[q] + v;
        }
    }
}

// ---------------------------------------------------------------------------
// SSD output (MFMA, fused diag+off+D*x), split in i-halves.
// ---------------------------------------------------------------------------
__global__ __launch_bounds__(256)
void ssd_out(const bf16_t* __restrict__ xBC, const float* __restrict__ dts,
             const bf16_t* __restrict__ G, const float* __restrict__ st,
             const float* __restrict__ acs_all, const float* __restrict__ D_head,
             bf16_t* __restrict__ y)
{
    const int bid = blockIdx.x;
    const int ih = bid & 1;
    const int h = (bid >> 1) & 15;
    const int c = (bid >> 5) & 15;
    const int b = bid >> 9;
    const int sbid = (b * NC + c) * NH + h;
    const int tid = threadIdx.x;
    const int lane = tid & 63;
    const int wave = tid >> 6;
    __shared__ float dtv[128];
    __shared__ float acs[128];
    __shared__ float eacs[64];
    __shared__ bf16_t Abuf[64 * LP];
    __shared__ bf16_t Bbuf[64 * LP];
    const long t0 = (long)b * S + (long)c * CH;
    const int m0b = ih * 64;

    if (tid < 128) {
        dtv[tid] = dts[(t0 + tid) * NH + h];
        acs[tid] = acs_all[(long)sbid * 128 + tid];
    }
    __syncthreads();
    if (tid < 64) eacs[tid] = __expf(acs[m0b + tid]);

    const bf16_t* Gb = G + (long)(b * NC + c) * 128 * 128;
    for (int i = tid; i < 4096; i += 256) {
        int rl = i >> 6, kp = (i & 63) << 1;
        int grow = m0b + rl;
        unsigned int g2 = *(const unsigned int*)&Gb[grow * 128 + kp];
        float w0 = (kp     <= grow) ? bfu2f((unsigned short)(g2      )) * __expf(acs[grow] - acs[kp    ]) * dtv[kp    ] : 0.f;
        float w1 = (kp + 1 <= grow) ? bfu2f((unsigned short)(g2 >> 16)) * __expf(acs[grow] - acs[kp + 1]) * dtv[kp + 1] : 0.f;
        *(unsigned int*)&Abuf[rl * LP + kp] = (unsigned)f2bfu(w0) | ((unsigned)f2bfu(w1) << 16);
    }
    for (int i = tid; i < 4096; i += 256) {
        int p = i & 63, jp = (i >> 6) << 1;
        unsigned short a = *(const unsigned short*)&xBC[(t0 + jp) * CDIM + h * HD + p];
        unsigned short bb = *(const unsigned short*)&xBC[(t0 + jp + 1) * CDIM + h * HD + p];
        *(unsigned int*)&Bbuf[p * LP + jp] = (unsigned)a | ((unsigned)bb << 16);
    }
    __syncthreads();

    const int kq = lane >> 4;
    const int lr = lane & 15;
    const int m0w = (wave & 1) * 32;
    const int p0 = (wave >> 1) * 32;
    f32x4 acc[2][2];
    #pragma unroll
    for (int i = 0; i < 2; i++)
        #pragma unroll
        for (int j = 0; j < 2; j++) acc[i][j] = (f32x4){0.f, 0.f, 0.f, 0.f};

    #pragma unroll
    for (int t = 0; t < 4; t++) {
        short8 af[2], bfr[2];
        #pragma unroll
        for (int i = 0; i < 2; i++)
            af[i] = *(const short8*)&Abuf[(m0w + i * 16 + lr) * LP + t * 32 + kq * 8];
        #pragma unroll
        for (int j = 0; j < 2; j++)
            bfr[j] = *(const short8*)&Bbuf[(p0 + j * 16 + lr) * LP + t * 32 + kq * 8];
        #pragma unroll
        for (int i = 0; i < 2; i++)
            #pragma unroll
            for (int j = 0; j < 2; j++)
                acc[i][j] = __builtin_amdgcn_mfma_f32_16x16x32_bf16(af[i], bfr[j], acc[i][j], 0, 0, 0);
    }
    const float Dh = D_head[h];
    float dx[2][2][4];
    #pragma unroll
    for (int i = 0; i < 2; i++)
        #pragma unroll
        for (int j = 0; j < 2; j++) {
            int col = p0 + j * 16 + lr;
            #pragma unroll
            for (int r = 0; r < 4; r++) {
                int rl = m0w + i * 16 + kq * 4 + r;
                dx[i][j][r] = Dh * __bfloat162float(Bbuf[col * LP + m0b + rl]);
            }
        }
    __syncthreads();

    for (int i = tid; i < 4096; i += 256) {
        int rl = i >> 6, np = (i & 63) << 1;
        unsigned int c2 = *(const unsigned int*)&xBC[(t0 + m0b + rl) * CDIM + DI + DSTATE + np];
        float e = eacs[rl];
        float v0 = e * bfu2f((unsigned short)(c2      ));
        float v1 = e * bfu2f((unsigned short)(c2 >> 16));
        *(unsigned int*)&Abuf[rl * LP + np] = (unsigned)f2bfu(v0) | ((unsigned)f2bfu(v1) << 16);
    }
    for (int i = tid; i < 4096; i += 256) {
        int p = i >> 6, np = (i & 63) << 1;
        float2 v = *(const float2*)&st[(long)sbid * 8192 + p * 128 + np];
        *(unsigned int*)&Bbuf[p * LP + np] = (unsigned)f2bfu(v.x) | ((unsigned)f2bfu(v.y) << 16);
    }
    __syncthreads();

    #pragma unroll
    for (int t = 0; t < 4; t++) {
        short8 af[2], bfr[2];
        #pragma unroll
        for (int i = 0; i < 2; i++)
            af[i] = *(const short8*)&Abuf[(m0w + i * 16 + lr) * LP + t * 32 + kq * 8];
        #pragma unroll
        for (int j = 0; j < 2; j++)
            bfr[j] = *(const short8*)&Bbuf[(p0 + j * 16 + lr) * LP + t * 32 + kq * 8];
        #pragma unroll
        for (int i = 0; i < 2; i++)
            #pragma unroll
            for (int j = 0; j < 2; j++)
                acc[i][j] = __builtin_amdgcn_mfma_f32_16x16x32_bf16(af[i], bfr[j], acc[i][j], 0, 0, 0);
    }

    #pragma unroll
    for (int i = 0; i < 2; i++)
        #pragma unroll
        for (int j = 0; j < 2; j++) {
            int col = p0 + j * 16 + lr;
            #pragma unroll
            for (int r = 0; r < 4; r++) {
                int rl = m0w + i * 16 + kq * 4 + r;
                y[(t0 + m0b + rl) * DI + h * HD + col] = __float2bfloat16(acc[i][j][r] + dx[i][j][r]);
            }
        }
}

// ---------------------------------------------------------------------------
// Gated RMSNorm, 8B/lane vector loads: thread owns 4 consecutive elements.
// ---------------------------------------------------------------------------
__global__ __launch_bounds__(256)
void gated_rms(const bf16_t* __restrict__ y, const bf16_t* __restrict__ zx,
               const float* __restrict__ norm_w, bf16_t* __restrict__ yn)
{
    const long t = blockIdx.x;
    const int d = threadIdx.x * 4;
    unsigned long long zu = *(const unsigned long long*)&zx[t * DIP + d];
    unsigned long long yu = *(const unsigned long long*)&y[t * DI + d];
    float g[4];
    float ss = 0.f, dummy = 0.f;
    #pragma unroll
    for (int q = 0; q < 4; q++) {
        float zv = bfu2f((unsigned short)(zu >> (16 * q)));
        float yv = bfu2f((unsigned short)(yu >> (16 * q)));
        float gv = yv * (zv / (1.f + __expf(-zv)));
        g[q] = gv;
        ss += gv * gv;
    }
    block_sum2(ss, dummy);
    float scale = rsqrtf(ss * (1.f / DI) + EPS);
    unsigned long long o = 0;
    #pragma unroll
    for (int q = 0; q < 4; q++)
        o |= (unsigned long long)f2bfu(g[q] * scale * norm_w[d + q]) << (16 * q);
    *(unsigned long long*)&yn[t * DI + d] = o;
}

// ---------------------------------------------------------------------------
// out = LayerNorm(x + r); 2 rows per block, float4 loads. W16: also bf16 copy.
// ---------------------------------------------------------------------------
template <bool W16>
__global__ __launch_bounds__(256)
void add_ln(const float* __restrict__ x, const float* __restrict__ r,
            const float* __restrict__ w, const float* __restrict__ bpar,
            float* __restrict__ o32, bf16_t* __restrict__ o16)
{
    const int tid = threadIdx.x;
    const long t = blockIdx.x * 2 + (tid >> 7);
    const int i = (tid & 127) * 4;
    float4 xv = *(const float4*)(x + t * DM + i);
    float4 rv = *(const float4*)(r + t * DM + i);
    float v[4] = {xv.x + rv.x, xv.y + rv.y, xv.z + rv.z, xv.w + rv.w};
    float s = v[0] + v[1] + v[2] + v[3];
    float s2 = v[0]*v[0] + v[1]*v[1] + v[2]*v[2] + v[3]*v[3];
    #pragma unroll
    for (int o = 32; o > 0; o >>= 1) {
        s += __shfl_down(s, o, 64);
        s2 += __shfl_down(s2, o, 64);
    }
    __shared__ float sa[4], sb[4];
    int wv = tid >> 6;
    if ((tid & 63) == 0) { sa[wv] = s; sb[wv] = s2; }
    __syncthreads();
    int base = (tid >> 7) * 2;
    s = sa[base] + sa[base + 1];
    s2 = sb[base] + sb[base + 1];
    float mean = s * (1.f / DM);
    float var = s2 * (1.f / DM) - mean * mean;
    float inv = rsqrtf(var + EPS);
    float4 ov;
    float* op = (float*)&ov;
    unsigned long long o16u = 0;
    #pragma unroll
    for (int q = 0; q < 4; q++) {
        float o = (v[q] - mean) * inv * w[i + q] + bpar[i + q];
        op[q] = o;
        if (W16) o16u |= (unsigned long long)f2bfu(o) << (16 * q);
    }
    *(float4*)(o32 + t * DM + i) = ov;
    if (W16) *(unsigned long long*)&o16[t * DM + i] = o16u;
}

// ---------------------------------------------------------------------------

extern "C" void kernel_launch(void* const* d_in, const int* in_sizes, int n_in,
                              void* d_out, int out_size, void* d_ws, size_t ws_size,
                              hipStream_t stream)
{
    const float* tgt       = (const float*)d_in[0];
    const float* in_proj_w = (const float*)d_in[5];
    const float* conv_w    = (const float*)d_in[6];
    const float* conv_b    = (const float*)d_in[7];
    const float* dt_bias   = (const float*)d_in[8];
    const float* A_log     = (const float*)d_in[9];
    const float* D_head    = (const float*)d_in[10];
    const float* norm_w    = (const float*)d_in[11];
    const float* out_proj_w= (const float*)d_in[12];
    const float* norm1_w   = (const float*)d_in[13];
    const float* norm1_b   = (const float*)d_in[14];
    const float* w1        = (const float*)d_in[15];
    const float* b1        = (const float*)d_in[16];
    const float* w2        = (const float*)d_in[17];
    const float* b2        = (const float*)d_in[18];
    const float* norm3_w   = (const float*)d_in[19];
    const float* norm3_b   = (const float*)d_in[20];
    float* out = (float*)d_out;

    float* ws = (float*)d_ws;

    const size_t SZ_INW  = (size_t)DIPP * DM / 2;
    const size_t SZ_OUTW = (size_t)DM * DI / 2;
    const size_t SZ_W1   = (size_t)FF * DM / 2;
    const size_t SZ_W2   = (size_t)DM * FF / 2;
    size_t wo = 0;
    bf16_t* inW  = (bf16_t*)(ws + wo); wo += SZ_INW;
    bf16_t* outW = (bf16_t*)(ws + wo); wo += SZ_OUTW;
    bf16_t* w1b  = (bf16_t*)(ws + wo); wo += SZ_W1;
    bf16_t* w2b  = (bf16_t*)(ws + wo); wo += SZ_W2;
    const size_t WB = wo;

    const size_t PB = (size_t)S * DM / 2            // tgt_bf
                    + (size_t)S * DIP / 2           // zx_bf
                    + (size_t)S * NH                // dts
                    + (size_t)S * CDIM / 2          // xBC_bf
                    + (size_t)NC * 128 * 128 / 2    // G (bf16)
                    + (size_t)NC * NH * 128         // acs
                    + (size_t)NC * NH               // cdl
                    + (size_t)S * DI                // y region
                    + (size_t)S * DI;               // st
    int NB = 0;
    for (int nb = 8; nb >= 1; nb >>= 1) {
        if (ws_size >= (WB + (size_t)nb * PB) * sizeof(float)) { NB = nb; break; }
    }
    if (NB == 0) return;

    {
        long n = (long)DIPP * DM;
        cvt_bf16_pad<<<(n + 255) / 256, 256, 0, stream>>>(in_proj_w, inW, DIP, n, DM);
        n = (long)DM * DI;
        cvt_bf16<<<(n / 4 + 255) / 256, 256, 0, stream>>>(out_proj_w, outW, n);
        n = (long)FF * DM;
        cvt_bf16<<<(n / 4 + 255) / 256, 256, 0, stream>>>(w1, w1b, n);
        n = (long)DM * FF;
        cvt_bf16<<<(n / 4 + 255) / 256, 256, 0, stream>>>(w2, w2b, n);
    }

    for (int b0 = 0; b0 < BB; b0 += NB) {
        const long Tg = (long)NB * S;
        size_t o = WB;
        bf16_t* tgt_bf = (bf16_t*)(ws + o); o += (size_t)Tg * DM / 2;
        bf16_t* zx     = (bf16_t*)(ws + o); o += (size_t)Tg * DIP / 2;
        float*  dts    = ws + o;            o += (size_t)Tg * NH;
        bf16_t* xBC    = (bf16_t*)(ws + o); o += (size_t)Tg * CDIM / 2;
        bf16_t* Gbuf   = (bf16_t*)(ws + o); o += (size_t)NB * NC * 128 * 128 / 2;
        float*  acs    = ws + o;            o += (size_t)NB * NC * NH * 128;
        float*  cdl    = ws + o;            o += (size_t)NB * NC * NH;
        float*  ybuf   = ws + o;            o += (size_t)Tg * DI;
        float*  st     = ws + o;            o += (size_t)Tg * DI;

        bf16_t* ybf = (bf16_t*)ybuf;
        bf16_t* yn  = (bf16_t*)st;
        float*  t2  = ybuf;
        float*  tb  = (float*)zx;
        bf16_t* tbb = (bf16_t*)(((float*)zx) + Tg * DM);
        bf16_t* h1  = (bf16_t*)ybuf;
        float*  fb  = (float*)xBC;

        const float* tgt_g = tgt + (long)b0 * S * DM;
        float* out_g = out + (long)b0 * S * DM;

        cvt_bf16<<<((Tg * DM) / 4 + 255) / 256, 256, 0, stream>>>(tgt_g, tgt_bf, Tg * DM);
        mfma_gemm<128, 0, false, true><<<dim3(DIPP / 128, Tg / 128, 1), 256, 0, stream>>>(
            tgt_bf, inW, nullptr, zx, DIP, DM, DM, DM, DIP, 0, 0, 0);
        // dt = softplus(tgt @ Wdt^T + dt_bias)  (f32, fused epilogue)
        gemm_kernel<2, true><<<dim3(1, Tg / 64, 1), 256, 0, stream>>>(
            tgt_g, in_proj_w + (long)(DI + CDIM) * DM, dt_bias, dts,
            Tg, NH, DM, DM, DM, NH, 0, 0, 0);
        conv_silu_t16<<<dim3(CDIM / 256, S / 64, NB), 256, 0, stream>>>(zx, conv_w, conv_b, xBC);
        mfma_gemm<128, 0, false, true><<<dim3(1, 1, NB * NC), 256, 0, stream>>>(
            xBC + DI + DSTATE, xBC + DI, nullptr, Gbuf,
            128, DSTATE, CDIM, CDIM, 128,
            (long)CH * CDIM, (long)CH * CDIM, (long)128 * 128);
        ssd_states<<<NB * NC * NH * 2, 256, 0, stream>>>(xBC, dts, A_log, st, acs, cdl);
        ssd_scan<<<dim3(NB * NH, 4), 256, 0, stream>>>(st, cdl);
        ssd_out<<<NB * NC * NH * 2, 256, 0, stream>>>(xBC, dts, Gbuf, st, acs, D_head, ybf);
        gated_rms<<<Tg, 256, 0, stream>>>(ybf, zx, norm_w, yn);
        mfma_gemm<64, 0, false, false><<<dim3(DM / 128, Tg / 64, 1), 256, 0, stream>>>(
            yn, outW, nullptr, t2, DM, DI, DI, DI, DM, 0, 0, 0);
        add_ln<true><<<Tg / 2, 256, 0, stream>>>(tgt_g, t2, norm1_w, norm1_b, tb, tbb);
        mfma_gemm<128, 1, true, true><<<dim3(FF / 128, Tg / 128, 1), 256, 0, stream>>>(
            tbb, w1b, b1, h1, FF, DM, DM, DM, FF, 0, 0, 0);
        mfma_gemm<64, 0, true, false><<<dim3(DM / 128, Tg / 64, 1), 256, 0, stream>>>(
            h1, w2b, b2, fb, DM, FF, FF, FF, DM, 0, 0, 0);
        add_ln<false><<<Tg / 2, 256, 0, stream>>>(tb, fb, norm3_w, norm3_b, out_g, nullptr);
    }
}